// Round 8
// baseline (162.078 us; speedup 1.0000x reference)
//
#include <hip/hip_runtime.h>
#include <hip/hip_bf16.h>

#define BB 4
#define SS 512
#define DD 1024
#define HH 16
#define KR 64
#define HDIM 64
#define THREE_D 3072
#define M_ROWS 2048
#define SCALE_F 0.125f

typedef __attribute__((ext_vector_type(8))) short short8;
typedef __attribute__((ext_vector_type(4))) float floatx4;

union F8 { short8 s; unsigned int u[4]; unsigned short h[8]; };

__device__ inline float bfu(unsigned short h){ union{unsigned int u; float f;} c; c.u = ((unsigned int)h) << 16; return c.f; }
__device__ inline unsigned short f2bf(float f){
    union{float f; unsigned int u;} c; c.f = f;
    unsigned int u = c.u;
    return (unsigned short)((u + 0x7fffu + ((u >> 16) & 1u)) >> 16);   // RNE
}

#define GLOAD_LDS16(g, l)                                                     \
    __builtin_amdgcn_global_load_lds(                                         \
        (const __attribute__((address_space(1))) unsigned int*)(g),           \
        (__attribute__((address_space(3))) unsigned int*)(l), 16, 0, 0)

// ---------------------------------------------------------------------------
// prep: fused cvtA (x->swizzled bf16) + cvtB(w_qkv) + cvtB(w_out) + mask
// ---------------------------------------------------------------------------
__global__ __launch_bounds__(256) void prep_kernel(
    const float* __restrict__ x, const float* __restrict__ w_qkv,
    const float* __restrict__ w_out, const int* __restrict__ routes,
    unsigned short* __restrict__ xb_sw, unsigned short* __restrict__ wb1_sw,
    unsigned short* __restrict__ wb2_sw, unsigned int* __restrict__ maskg)
{
    const int bx = blockIdx.x;
    const int tid = threadIdx.x;
    if (bx < 1024) {
        int gid = bx * 256 + tid;
        int r  = gid & 127;
        int c  = (gid >> 7) & 3;
        int kt = (gid >> 9) & 31;
        int mt = gid >> 14;
        const float* src = x + ((size_t)(mt * 128 + r)) * 1024 + kt * 32 + c * 8;
        float4 a = *(const float4*)src;
        float4 b = *(const float4*)(src + 4);
        F8 o;
        o.h[0] = f2bf(a.x); o.h[1] = f2bf(a.y); o.h[2] = f2bf(a.z); o.h[3] = f2bf(a.w);
        o.h[4] = f2bf(b.x); o.h[5] = f2bf(b.y); o.h[6] = f2bf(b.z); o.h[7] = f2bf(b.w);
        *(uint4*)(xb_sw + (size_t)gid * 8) = *(uint4*)&o;
    } else if (bx < 3072) {
        const float* w;
        unsigned short* out;
        int gid, N;
        if (bx < 2560) { w = w_qkv; out = wb1_sw; N = THREE_D; gid = (bx - 1024) * 256 + tid; }
        else           { w = w_out; out = wb2_sw; N = DD;      gid = (bx - 2560) * 256 + tid; }
        int r  = gid & 127;
        int c  = (gid >> 7) & 3;
        int kt = (gid >> 9) & 31;
        int nt = gid >> 14;
        int n = nt * 128 + r;
        int kbase = kt * 32 + c * 8;
        F8 o;
#pragma unroll
        for (int j = 0; j < 8; ++j)
            o.h[j] = f2bf(w[(size_t)(kbase + j) * N + n]);
        *(uint4*)(out + (size_t)gid * 8) = *(uint4*)&o;
    } else {
        int q = (bx - 3072) * 256 + tid;
        unsigned int w[16];
#pragma unroll
        for (int i = 0; i < 16; ++i) w[i] = 0u;
        for (int j = 0; j < KR; ++j) {
            int r = routes[q * KR + j];
            if (r <= q) w[r >> 5] |= 1u << (r & 31);
        }
#pragma unroll
        for (int sw = 0; sw < 16; ++sw) maskg[sw * SS + q] = w[sw];
    }
}

// ---------------------------------------------------------------------------
// GEMM1 (QKV): 128x128 tile, BK=64, global_load_lds staging, LDS-assembled
// coalesced bf16 epilogue into q/k/v [B,H,S,HD] bf16.
// ---------------------------------------------------------------------------
__global__ __launch_bounds__(256) void gemm_qkv(
    const unsigned short* __restrict__ Asw,
    const unsigned short* __restrict__ Bsw,
    const float* __restrict__ bias,
    unsigned short* __restrict__ qb, unsigned short* __restrict__ kb,
    unsigned short* __restrict__ vb)
{
    __shared__ __align__(16) unsigned short Sh[17408];   // 34816 B (union)
    unsigned short* Alds = Sh;
    unsigned short* Blds = Sh + 8192;

    const int tid  = threadIdx.x;
    const int lane = tid & 63;
    const int wid  = tid >> 6;
    const int l15  = lane & 15;
    const int quad = lane >> 4;
    const int wm   = (wid >> 1) * 64;
    const int wn   = (wid & 1) * 64;

    const unsigned short* Ak = Asw + (size_t)blockIdx.y * 131072;
    const unsigned short* Bk = Bsw + (size_t)blockIdx.x * 131072;

    floatx4 acc[4][4];
#pragma unroll
    for (int i = 0; i < 4; ++i)
#pragma unroll
        for (int j = 0; j < 4; ++j) acc[i][j] = (floatx4){0.f, 0.f, 0.f, 0.f};

    for (int kt2 = 0; kt2 < 16; ++kt2) {
#pragma unroll
        for (int kh = 0; kh < 2; ++kh) {
            const unsigned short* ga = Ak + (kt2 * 2 + kh) * 4096 + wid * 1024 + lane * 8;
            const unsigned short* gb = Bk + (kt2 * 2 + kh) * 4096 + wid * 1024 + lane * 8;
            GLOAD_LDS16(ga,       Alds + kh * 4096 + wid * 1024 + lane * 8);
            GLOAD_LDS16(ga + 512, Alds + kh * 4096 + wid * 1024 + 512 + lane * 8);
            GLOAD_LDS16(gb,       Blds + kh * 4096 + wid * 1024 + lane * 8);
            GLOAD_LDS16(gb + 512, Blds + kh * 4096 + wid * 1024 + 512 + lane * 8);
        }
        __syncthreads();

#pragma unroll
        for (int kh = 0; kh < 2; ++kh) {
            F8 af[4], bf[4];
#pragma unroll
            for (int mi = 0; mi < 4; ++mi)
                af[mi] = *(const F8*)(Alds + kh * 4096 + (size_t)(quad * 128 + wm + mi * 16 + l15) * 8);
#pragma unroll
            for (int ni = 0; ni < 4; ++ni)
                bf[ni] = *(const F8*)(Blds + kh * 4096 + (size_t)(quad * 128 + wn + ni * 16 + l15) * 8);
#pragma unroll
            for (int mi = 0; mi < 4; ++mi)
#pragma unroll
                for (int ni = 0; ni < 4; ++ni)
                    acc[mi][ni] = __builtin_amdgcn_mfma_f32_16x16x32_bf16(
                        af[mi].s, bf[ni].s, acc[mi][ni], 0, 0, 0);
        }
        __syncthreads();
    }

    const int m0 = blockIdx.y * 128;
    const int n0 = blockIdx.x * 128;

#pragma unroll
    for (int mi = 0; mi < 4; ++mi) {
#pragma unroll
        for (int ni = 0; ni < 4; ++ni) {
            int col = wn + ni * 16 + l15;
            float bv = bias[n0 + col];
#pragma unroll
            for (int r = 0; r < 4; ++r) {
                int row = wm + mi * 16 + quad * 4 + r;
                Sh[row * 136 + col] = f2bf(acc[mi][ni][r] + bv);
            }
        }
    }
    __syncthreads();

    for (int i = tid; i < 2048; i += 256) {
        int rr = i >> 4, cc = i & 15;
        int grow = m0 + rr, gcol = n0 + cc * 8;
        int b = grow >> 9, s = grow & 511;
        int which = gcol >> 10, rem = gcol & 1023;
        int h = rem >> 6, hd = rem & 63;
        unsigned short* dst = (which == 0) ? qb : (which == 1) ? kb : vb;
        uint4 val = *(const uint4*)(Sh + rr * 136 + cc * 8);
        *(uint4*)(dst + (((size_t)(b * HH + h) * SS) + s) * HDIM + hd) = val;
    }
}

// ---------------------------------------------------------------------------
// GEMM2 (out proj): 64x128 tile, BK=64 -> 256 blocks, fp32 output.
// ---------------------------------------------------------------------------
__global__ __launch_bounds__(256) void gemm_out(
    const unsigned short* __restrict__ Asw,
    const unsigned short* __restrict__ Bsw,
    const float* __restrict__ bias,
    float* __restrict__ Cout)
{
    __shared__ __align__(16) unsigned short Alds[4096];
    __shared__ __align__(16) unsigned short Blds[8192];

    const int tid  = threadIdx.x;
    const int lane = tid & 63;
    const int wid  = tid >> 6;
    const int l15  = lane & 15;
    const int quad = lane >> 4;
    const int mt64 = blockIdx.y;
    const int mt   = mt64 >> 1;
    const int rh   = (mt64 & 1) * 64;
    const int nt   = blockIdx.x;
    const int wn   = wid * 32;

    floatx4 acc[4][2];
#pragma unroll
    for (int i = 0; i < 4; ++i)
#pragma unroll
        for (int j = 0; j < 2; ++j) acc[i][j] = (floatx4){0.f, 0.f, 0.f, 0.f};

    for (int kt2 = 0; kt2 < 16; ++kt2) {
#pragma unroll
        for (int kh = 0; kh < 2; ++kh) {
            int kt = kt2 * 2 + kh;
            const unsigned short* ga = Asw + ((size_t)(mt * 32 + kt) * 4 + wid) * 1024 + (rh + lane) * 8;
            const unsigned short* gb = Bsw + (size_t)(nt * 32 + kt) * 4096 + wid * 1024 + lane * 8;
            GLOAD_LDS16(ga,       Alds + kh * 2048 + wid * 512 + lane * 8);
            GLOAD_LDS16(gb,       Blds + kh * 4096 + wid * 1024 + lane * 8);
            GLOAD_LDS16(gb + 512, Blds + kh * 4096 + wid * 1024 + 512 + lane * 8);
        }
        __syncthreads();

#pragma unroll
        for (int kh = 0; kh < 2; ++kh) {
            F8 af[4], bf[2];
#pragma unroll
            for (int mi = 0; mi < 4; ++mi)
                af[mi] = *(const F8*)(Alds + kh * 2048 + (size_t)(quad * 64 + mi * 16 + l15) * 8);
#pragma unroll
            for (int ni = 0; ni < 2; ++ni)
                bf[ni] = *(const F8*)(Blds + kh * 4096 + (size_t)(quad * 128 + wn + ni * 16 + l15) * 8);
#pragma unroll
            for (int mi = 0; mi < 4; ++mi)
#pragma unroll
                for (int ni = 0; ni < 2; ++ni)
                    acc[mi][ni] = __builtin_amdgcn_mfma_f32_16x16x32_bf16(
                        af[mi].s, bf[ni].s, acc[mi][ni], 0, 0, 0);
        }
        __syncthreads();
    }

    const int m0 = mt64 * 64;
    const int n0 = nt * 128;
#pragma unroll
    for (int mi = 0; mi < 4; ++mi) {
#pragma unroll
        for (int ni = 0; ni < 2; ++ni) {
            int col = n0 + wn + ni * 16 + l15;
            float bv = bias[col];
#pragma unroll
            for (int r = 0; r < 4; ++r) {
                int row = m0 + mi * 16 + quad * 4 + r;
                Cout[(size_t)row * DD + col] = acc[mi][ni][r] + bv;
            }
        }
    }
}

// ---------------------------------------------------------------------------
// Dense masked flash attention via MFMA. K' AND V' both blended inline
// during staging (V additionally transposed via scalar swizzled LDS writes).
// No max-subtraction (scores bounded); mask folded into exp pass.
// Output written in swizzled chunk layout for gemm2.
// ---------------------------------------------------------------------------
__global__ __launch_bounds__(512, 2) void attn_kernel(
    const unsigned short* __restrict__ qb,
    const unsigned short* __restrict__ kbuf,  // raw K bf16 [B,H,S,HD]
    const unsigned short* __restrict__ vbuf,  // raw V bf16 [B,H,S,HD]
    const unsigned int* __restrict__ maskg,
    unsigned short* __restrict__ attn_sw)
{
    __shared__ __align__(16) unsigned short Ks[512 * 64];
    __shared__ __align__(16) unsigned short Vs[64 * 512];
    __shared__ __align__(16) unsigned short Ps[8 * 16 * 64];

    const int bh = blockIdx.x >> 2;
    const int qt = blockIdx.x & 3;
    const int b = bh >> 4, h = bh & 15;
    const int tid  = threadIdx.x;
    const int lane = tid & 63;
    const int wid  = tid >> 6;
    const int l15  = lane & 15;
    const int quad = lane >> 4;

    {
        // K' = blend(K), row-major swizzled chunks (b128 writes)
        const unsigned short* kbh = kbuf + (size_t)bh * (SS * 64);
        uint4* dst = (uint4*)Ks;
        for (int c = tid; c < 4096; c += 512) {
            int s = c >> 3, cc = c & 7;
            int sm = s ? s - 1 : 0;
            int sp = (s < SS - 1) ? s + 1 : SS - 1;
            F8 k0 = *(const F8*)(kbh + (size_t)s  * 64 + cc * 8);
            F8 km = *(const F8*)(kbh + (size_t)sm * 64 + cc * 8);
            F8 kp = *(const F8*)(kbh + (size_t)sp * 64 + cc * 8);
            F8 o;
#pragma unroll
            for (int j = 0; j < 8; ++j)
                o.h[j] = f2bf(0.75f * bfu(k0.h[j]) + 0.125f * (bfu(km.h[j]) + bfu(kp.h[j])));
            dst[(s << 3) | (cc ^ (s & 7))] = *(uint4*)&o;
        }
        // V' = blend(V), transposed [d][s] via scalar swizzled writes.
        // chunk(d,sc) = (d<<6)|(sc&56)|((sc^d^(d>>3))&7): writes AND b128
        // frag reads both <=2-way.
        const unsigned short* vbh = vbuf + (size_t)bh * (SS * 64);
        const int a8 = tid & 7;
        const int cc = (tid >> 3) & 7;
        const int s0 = ((tid >> 6) << 3) + a8;
#pragma unroll
        for (int k = 0; k < 8; ++k) {
            int s = s0 + k * 64;
            int sm = s ? s - 1 : 0;
            int sp = (s < SS - 1) ? s + 1 : SS - 1;
            F8 v0 = *(const F8*)(vbh + (size_t)s  * 64 + cc * 8);
            F8 vm = *(const F8*)(vbh + (size_t)sm * 64 + cc * 8);
            F8 vp = *(const F8*)(vbh + (size_t)sp * 64 + cc * 8);
            int sc = s >> 3;
#pragma unroll
            for (int j = 0; j < 8; ++j) {
                int d = cc * 8 + j;
                float bv = 0.75f * bfu(v0.h[j]) + 0.125f * (bfu(vm.h[j]) + bfu(vp.h[j]));
                int chunk = (d << 6) | (sc & 56) | ((sc ^ d ^ cc) & 7);
                Vs[(chunk << 3) | (s & 7)] = f2bf(bv);
            }
        }
    }
    __syncthreads();

    const int qbase = qt * 128 + wid * 16;
    const int q = qbase + l15;

    F8 qf[2];
    {
        const unsigned short* qrow = qb + ((size_t)bh * SS + q) * 64;
        qf[0] = *(const F8*)(qrow + quad * 8);
        qf[1] = *(const F8*)(qrow + 32 + quad * 8);
    }

    // ---- S^T phase: raw scores (no mask/max pass needed; scores bounded)
    floatx4 accS[32];
#pragma unroll
    for (int st = 0; st < 32; ++st) {
        int srow = st * 16 + l15;
        const F8 k0 = *(const F8*)(Ks + (((srow << 3) | ( quad      ^ (srow & 7))) << 3));
        const F8 k1 = *(const F8*)(Ks + (((srow << 3) | ((4 + quad) ^ (srow & 7))) << 3));
        floatx4 a = (floatx4){0.f, 0.f, 0.f, 0.f};
        a = __builtin_amdgcn_mfma_f32_16x16x32_bf16(k0.s, qf[0].s, a, 0, 0, 0);
        a = __builtin_amdgcn_mfma_f32_16x16x32_bf16(k1.s, qf[1].s, a, 0, 0, 0);
        accS[st] = a;
    }

    // ---- PV phase: mask*exp fused, P -> swizzled per-wave LDS -> MFMA
    floatx4 accO[4];
#pragma unroll
    for (int dt = 0; dt < 4; ++dt) accO[dt] = (floatx4){0.f, 0.f, 0.f, 0.f};
    float lsum = 0.f;
    unsigned int* Pw = (unsigned int*)Ps + wid * 512;

#pragma unroll
    for (int ch = 0; ch < 8; ++ch) {
        unsigned int mw0 = maskg[(ch * 2) * SS + q];
        unsigned int mw1 = maskg[(ch * 2 + 1) * SS + q];
#pragma unroll
        for (int t = 0; t < 4; ++t) {
            unsigned int mw = (t & 2) ? mw1 : mw0;
            int sbase = (t & 1) * 16 + quad * 4;
            floatx4 a = accS[ch * 4 + t];
            float e0 = ((mw >> (sbase + 0)) & 1u) ? __expf(a[0] * SCALE_F) : 0.f;
            float e1 = ((mw >> (sbase + 1)) & 1u) ? __expf(a[1] * SCALE_F) : 0.f;
            float e2 = ((mw >> (sbase + 2)) & 1u) ? __expf(a[2] * SCALE_F) : 0.f;
            float e3 = ((mw >> (sbase + 3)) & 1u) ? __expf(a[3] * SCALE_F) : 0.f;
            lsum += (e0 + e1) + (e2 + e3);
            unsigned int w0 = (unsigned int)f2bf(e0) | ((unsigned int)f2bf(e1) << 16);
            unsigned int w1 = (unsigned int)f2bf(e2) | ((unsigned int)f2bf(e3) << 16);
            int off0 = t * 8 + quad * 2;
            int off1 = off0 + 1;
            Pw[l15 * 32 + ((((off0 >> 2) ^ (l15 & 7)) << 2) | (off0 & 3))] = w0;
            Pw[l15 * 32 + ((((off1 >> 2) ^ (l15 & 7)) << 2) | (off1 & 3))] = w1;
        }
        F8 pa[2];
#pragma unroll
        for (int ks = 0; ks < 2; ++ks) {
            int ci = ks * 4 + quad;
            pa[ks] = *(const F8*)((const unsigned short*)(Pw + l15 * 32) +
                                  ((ci ^ (l15 & 7)) << 3));
        }
#pragma unroll
        for (int dt = 0; dt < 4; ++dt) {
            int d = dt * 16 + l15;
#pragma unroll
            for (int ks = 0; ks < 2; ++ks) {
                int sc = ch * 8 + ks * 4 + quad;
                int chunk = (d << 6) | (sc & 56) | ((sc ^ d ^ (d >> 3)) & 7);
                const F8 bv = *(const F8*)(Vs + (chunk << 3));
                accO[dt] = __builtin_amdgcn_mfma_f32_16x16x32_bf16(pa[ks].s, bv.s, accO[dt], 0, 0, 0);
            }
        }
    }

    lsum += __shfl_xor(lsum, 16);
    lsum += __shfl_xor(lsum, 32);
    float inv = 1.0f / lsum;

    unsigned short* Ow = Ps + wid * 1024;
#pragma unroll
    for (int r = 0; r < 4; ++r) {
        float invr = __shfl(inv, quad * 4 + r);
#pragma unroll
        for (int dt = 0; dt < 4; ++dt)
            Ow[(quad * 4 + r) * 64 + dt * 16 + l15] = f2bf(accO[dt][r] * invr);
    }
#pragma unroll
    for (int i = 0; i < 2; ++i) {
        int ch = i * 64 + lane;
        int qlocal = ch >> 3, j = ch & 7;
        int qq = qt * 128 + wid * 16 + qlocal;
        int mrow = b * SS + qq;
        int mt = mrow >> 7, rr = mrow & 127;
        int kt2 = h * 2 + (j >> 2), c = j & 3;
        size_t gid = (((size_t)(mt * 32 + kt2) * 4 + c) * 128 + rr);
        *(uint4*)(attn_sw + gid * 8) = *(const uint4*)(Ow + qlocal * 64 + j * 8);
    }
}

// ---------------------------------------------------------------------------
extern "C" void kernel_launch(void* const* d_in, const int* in_sizes, int n_in,
                              void* d_out, int out_size, void* d_ws, size_t ws_size,
                              hipStream_t stream)
{
    const float* x     = (const float*)d_in[0];
    const float* w_qkv = (const float*)d_in[1];
    const float* b_qkv = (const float*)d_in[2];
    const float* w_out = (const float*)d_in[3];
    const float* b_out = (const float*)d_in[4];
    const int* routes  = (const int*)d_in[5];

    char* w = (char*)d_ws;
    unsigned short* xb_sw  = (unsigned short*)(w);                 // 4 MB
    unsigned short* wb1_sw = (unsigned short*)(w + (4u  << 20));   // 6 MB
    unsigned short* wb2_sw = (unsigned short*)(w + (10u << 20));   // 2 MB
    unsigned short* qbuf   = (unsigned short*)(w + (12u << 20));   // 4 MB
    unsigned short* kbuf   = (unsigned short*)(w + (16u << 20));   // 4 MB
    unsigned short* vbuf   = (unsigned short*)(w + (20u << 20));   // 4 MB
    unsigned short* attnsw = (unsigned short*)(w + (24u << 20));   // 4 MB
    unsigned int*   maskg  = (unsigned int*)(w + (28u << 20));     // 32 KB

    prep_kernel<<<3074, 256, 0, stream>>>(x, w_qkv, w_out, routes,
                                          xb_sw, wb1_sw, wb2_sw, maskg);

    gemm_qkv<<<dim3(THREE_D / 128, M_ROWS / 128), 256, 0, stream>>>(
        xb_sw, wb1_sw, b_qkv, qbuf, kbuf, vbuf);

    attn_kernel<<<256, 512, 0, stream>>>(qbuf, kbuf, vbuf, maskg, attnsw);

    gemm_out<<<dim3(DD / 128, M_ROWS / 64), 256, 0, stream>>>(
        attnsw, wb2_sw, b_out, (float*)d_out);
}

// Round 9
// 156.456 us; speedup vs baseline: 1.0359x; 1.0359x over previous
//
#include <hip/hip_runtime.h>
#include <hip/hip_bf16.h>

#define BB 4
#define SS 512
#define DD 1024
#define HH 16
#define KR 64
#define HDIM 64
#define THREE_D 3072
#define M_ROWS 2048
#define SCALE_F 0.125f

typedef __attribute__((ext_vector_type(8))) short short8;
typedef __attribute__((ext_vector_type(4))) float floatx4;

union F8 { short8 s; unsigned int u[4]; unsigned short h[8]; };

__device__ inline float bfu(unsigned short h){ union{unsigned int u; float f;} c; c.u = ((unsigned int)h) << 16; return c.f; }
__device__ inline unsigned short f2bf(float f){
    union{float f; unsigned int u;} c; c.f = f;
    unsigned int u = c.u;
    return (unsigned short)((u + 0x7fffu + ((u >> 16) & 1u)) >> 16);   // RNE
}

#define GLOAD_LDS16(g, l)                                                     \
    __builtin_amdgcn_global_load_lds(                                         \
        (const __attribute__((address_space(1))) unsigned int*)(g),           \
        (__attribute__((address_space(3))) unsigned int*)(l), 16, 0, 0)

// ---------------------------------------------------------------------------
// prep: fused cvtA (x->swizzled bf16) + cvtB(w_qkv) + cvtB(w_out) + mask
// ---------------------------------------------------------------------------
__global__ __launch_bounds__(256) void prep_kernel(
    const float* __restrict__ x, const float* __restrict__ w_qkv,
    const float* __restrict__ w_out, const int* __restrict__ routes,
    unsigned short* __restrict__ xb_sw, unsigned short* __restrict__ wb1_sw,
    unsigned short* __restrict__ wb2_sw, unsigned int* __restrict__ maskg)
{
    const int bx = blockIdx.x;
    const int tid = threadIdx.x;
    if (bx < 1024) {
        int gid = bx * 256 + tid;
        int r  = gid & 127;
        int c  = (gid >> 7) & 3;
        int kt = (gid >> 9) & 31;
        int mt = gid >> 14;
        const float* src = x + ((size_t)(mt * 128 + r)) * 1024 + kt * 32 + c * 8;
        float4 a = *(const float4*)src;
        float4 b = *(const float4*)(src + 4);
        F8 o;
        o.h[0] = f2bf(a.x); o.h[1] = f2bf(a.y); o.h[2] = f2bf(a.z); o.h[3] = f2bf(a.w);
        o.h[4] = f2bf(b.x); o.h[5] = f2bf(b.y); o.h[6] = f2bf(b.z); o.h[7] = f2bf(b.w);
        *(uint4*)(xb_sw + (size_t)gid * 8) = *(uint4*)&o;
    } else if (bx < 3072) {
        const float* w;
        unsigned short* out;
        int gid, N;
        if (bx < 2560) { w = w_qkv; out = wb1_sw; N = THREE_D; gid = (bx - 1024) * 256 + tid; }
        else           { w = w_out; out = wb2_sw; N = DD;      gid = (bx - 2560) * 256 + tid; }
        int r  = gid & 127;
        int c  = (gid >> 7) & 3;
        int kt = (gid >> 9) & 31;
        int nt = gid >> 14;
        int n = nt * 128 + r;
        int kbase = kt * 32 + c * 8;
        F8 o;
#pragma unroll
        for (int j = 0; j < 8; ++j)
            o.h[j] = f2bf(w[(size_t)(kbase + j) * N + n]);
        *(uint4*)(out + (size_t)gid * 8) = *(uint4*)&o;
    } else {
        int q = (bx - 3072) * 256 + tid;
        unsigned int w[16];
#pragma unroll
        for (int i = 0; i < 16; ++i) w[i] = 0u;
        for (int j = 0; j < KR; ++j) {
            int r = routes[q * KR + j];
            if (r <= q) w[r >> 5] |= 1u << (r & 31);
        }
#pragma unroll
        for (int sw = 0; sw < 16; ++sw) maskg[sw * SS + q] = w[sw];
    }
}

// ---------------------------------------------------------------------------
// GEMM1 (QKV): 128x128 tile, BK=64, global_load_lds staging, LDS-assembled
// coalesced bf16 epilogue into q/k/v [B,H,S,HD] bf16.
// ---------------------------------------------------------------------------
__global__ __launch_bounds__(256) void gemm_qkv(
    const unsigned short* __restrict__ Asw,
    const unsigned short* __restrict__ Bsw,
    const float* __restrict__ bias,
    unsigned short* __restrict__ qb, unsigned short* __restrict__ kb,
    unsigned short* __restrict__ vb)
{
    __shared__ __align__(16) unsigned short Sh[17408];   // 34816 B (union)
    unsigned short* Alds = Sh;
    unsigned short* Blds = Sh + 8192;

    const int tid  = threadIdx.x;
    const int lane = tid & 63;
    const int wid  = tid >> 6;
    const int l15  = lane & 15;
    const int quad = lane >> 4;
    const int wm   = (wid >> 1) * 64;
    const int wn   = (wid & 1) * 64;

    const unsigned short* Ak = Asw + (size_t)blockIdx.y * 131072;
    const unsigned short* Bk = Bsw + (size_t)blockIdx.x * 131072;

    floatx4 acc[4][4];
#pragma unroll
    for (int i = 0; i < 4; ++i)
#pragma unroll
        for (int j = 0; j < 4; ++j) acc[i][j] = (floatx4){0.f, 0.f, 0.f, 0.f};

    for (int kt2 = 0; kt2 < 16; ++kt2) {
#pragma unroll
        for (int kh = 0; kh < 2; ++kh) {
            const unsigned short* ga = Ak + (kt2 * 2 + kh) * 4096 + wid * 1024 + lane * 8;
            const unsigned short* gb = Bk + (kt2 * 2 + kh) * 4096 + wid * 1024 + lane * 8;
            GLOAD_LDS16(ga,       Alds + kh * 4096 + wid * 1024 + lane * 8);
            GLOAD_LDS16(ga + 512, Alds + kh * 4096 + wid * 1024 + 512 + lane * 8);
            GLOAD_LDS16(gb,       Blds + kh * 4096 + wid * 1024 + lane * 8);
            GLOAD_LDS16(gb + 512, Blds + kh * 4096 + wid * 1024 + 512 + lane * 8);
        }
        __syncthreads();

#pragma unroll
        for (int kh = 0; kh < 2; ++kh) {
            F8 af[4], bf[4];
#pragma unroll
            for (int mi = 0; mi < 4; ++mi)
                af[mi] = *(const F8*)(Alds + kh * 4096 + (size_t)(quad * 128 + wm + mi * 16 + l15) * 8);
#pragma unroll
            for (int ni = 0; ni < 4; ++ni)
                bf[ni] = *(const F8*)(Blds + kh * 4096 + (size_t)(quad * 128 + wn + ni * 16 + l15) * 8);
#pragma unroll
            for (int mi = 0; mi < 4; ++mi)
#pragma unroll
                for (int ni = 0; ni < 4; ++ni)
                    acc[mi][ni] = __builtin_amdgcn_mfma_f32_16x16x32_bf16(
                        af[mi].s, bf[ni].s, acc[mi][ni], 0, 0, 0);
        }
        __syncthreads();
    }

    const int m0 = blockIdx.y * 128;
    const int n0 = blockIdx.x * 128;

#pragma unroll
    for (int mi = 0; mi < 4; ++mi) {
#pragma unroll
        for (int ni = 0; ni < 4; ++ni) {
            int col = wn + ni * 16 + l15;
            float bv = bias[n0 + col];
#pragma unroll
            for (int r = 0; r < 4; ++r) {
                int row = wm + mi * 16 + quad * 4 + r;
                Sh[row * 136 + col] = f2bf(acc[mi][ni][r] + bv);
            }
        }
    }
    __syncthreads();

    for (int i = tid; i < 2048; i += 256) {
        int rr = i >> 4, cc = i & 15;
        int grow = m0 + rr, gcol = n0 + cc * 8;
        int b = grow >> 9, s = grow & 511;
        int which = gcol >> 10, rem = gcol & 1023;
        int h = rem >> 6, hd = rem & 63;
        unsigned short* dst = (which == 0) ? qb : (which == 1) ? kb : vb;
        uint4 val = *(const uint4*)(Sh + rr * 136 + cc * 8);
        *(uint4*)(dst + (((size_t)(b * HH + h) * SS) + s) * HDIM + hd) = val;
    }
}

// ---------------------------------------------------------------------------
// GEMM2 (out proj): 64x128 tile, BK=64 -> 256 blocks, fp32 output.
// ---------------------------------------------------------------------------
__global__ __launch_bounds__(256) void gemm_out(
    const unsigned short* __restrict__ Asw,
    const unsigned short* __restrict__ Bsw,
    const float* __restrict__ bias,
    float* __restrict__ Cout)
{
    __shared__ __align__(16) unsigned short Alds[4096];
    __shared__ __align__(16) unsigned short Blds[8192];

    const int tid  = threadIdx.x;
    const int lane = tid & 63;
    const int wid  = tid >> 6;
    const int l15  = lane & 15;
    const int quad = lane >> 4;
    const int mt64 = blockIdx.y;
    const int mt   = mt64 >> 1;
    const int rh   = (mt64 & 1) * 64;
    const int nt   = blockIdx.x;
    const int wn   = wid * 32;

    floatx4 acc[4][2];
#pragma unroll
    for (int i = 0; i < 4; ++i)
#pragma unroll
        for (int j = 0; j < 2; ++j) acc[i][j] = (floatx4){0.f, 0.f, 0.f, 0.f};

    for (int kt2 = 0; kt2 < 16; ++kt2) {
#pragma unroll
        for (int kh = 0; kh < 2; ++kh) {
            int kt = kt2 * 2 + kh;
            const unsigned short* ga = Asw + ((size_t)(mt * 32 + kt) * 4 + wid) * 1024 + (rh + lane) * 8;
            const unsigned short* gb = Bsw + (size_t)(nt * 32 + kt) * 4096 + wid * 1024 + lane * 8;
            GLOAD_LDS16(ga,       Alds + kh * 2048 + wid * 512 + lane * 8);
            GLOAD_LDS16(gb,       Blds + kh * 4096 + wid * 1024 + lane * 8);
            GLOAD_LDS16(gb + 512, Blds + kh * 4096 + wid * 1024 + 512 + lane * 8);
        }
        __syncthreads();

#pragma unroll
        for (int kh = 0; kh < 2; ++kh) {
            F8 af[4], bf[2];
#pragma unroll
            for (int mi = 0; mi < 4; ++mi)
                af[mi] = *(const F8*)(Alds + kh * 2048 + (size_t)(quad * 64 + mi * 16 + l15) * 8);
#pragma unroll
            for (int ni = 0; ni < 2; ++ni)
                bf[ni] = *(const F8*)(Blds + kh * 4096 + (size_t)(quad * 128 + wn + ni * 16 + l15) * 8);
#pragma unroll
            for (int mi = 0; mi < 4; ++mi)
#pragma unroll
                for (int ni = 0; ni < 2; ++ni)
                    acc[mi][ni] = __builtin_amdgcn_mfma_f32_16x16x32_bf16(
                        af[mi].s, bf[ni].s, acc[mi][ni], 0, 0, 0);
        }
        __syncthreads();
    }

    const int m0 = mt64 * 64;
    const int n0 = nt * 128;
#pragma unroll
    for (int mi = 0; mi < 4; ++mi) {
#pragma unroll
        for (int ni = 0; ni < 2; ++ni) {
            int col = n0 + wn + ni * 16 + l15;
            float bv = bias[col];
#pragma unroll
            for (int r = 0; r < 4; ++r) {
                int row = m0 + mi * 16 + quad * 4 + r;
                Cout[(size_t)row * DD + col] = acc[mi][ni][r] + bv;
            }
        }
    }
}

// ---------------------------------------------------------------------------
// blend V only: V't[d][s] bf16 (per bh); K' is blended inline in attn.
// ---------------------------------------------------------------------------
__global__ __launch_bounds__(256) void blend_v_kernel(
    const unsigned short* __restrict__ vb, unsigned short* __restrict__ Vtg)
{
    __shared__ float vt[130][65];
    const int bh = blockIdx.x >> 2;
    const int sb = (blockIdx.x & 3) * 128;
    const int tid = threadIdx.x;
    const unsigned short* vbase = vb + (size_t)bh * SS * HDIM;

    for (int i = tid; i < 130 * 8; i += 256) {
        int row = i >> 3, c8 = (i & 7) << 3;
        int s = sb + row - 1; s = s < 0 ? 0 : (s > SS - 1 ? SS - 1 : s);
        F8 vv = *(const F8*)(vbase + (size_t)s * 64 + c8);
#pragma unroll
        for (int j = 0; j < 8; ++j) vt[row][c8 + j] = bfu(vv.h[j]);
    }
    __syncthreads();

    for (int i = tid; i < 64 * 32; i += 256) {
        int d = i >> 5, s4 = (i & 31) << 2;
        ushort4 o;
        o.x = f2bf(0.75f * vt[s4+1][d] + 0.125f * (vt[s4+0][d] + vt[s4+2][d]));
        o.y = f2bf(0.75f * vt[s4+2][d] + 0.125f * (vt[s4+1][d] + vt[s4+3][d]));
        o.z = f2bf(0.75f * vt[s4+3][d] + 0.125f * (vt[s4+2][d] + vt[s4+4][d]));
        o.w = f2bf(0.75f * vt[s4+4][d] + 0.125f * (vt[s4+3][d] + vt[s4+5][d]));
        *(ushort4*)(Vtg + ((size_t)bh * 64 + d) * SS + sb + s4) = o;
    }
}

// ---------------------------------------------------------------------------
// Dense masked flash attention via MFMA; K' blended inline during staging;
// no max pass (scores bounded), mask folded into exp; swizzled-chunk output.
// ---------------------------------------------------------------------------
__global__ __launch_bounds__(512, 2) void attn_kernel(
    const unsigned short* __restrict__ qb,
    const unsigned short* __restrict__ kbuf,  // raw K bf16 [B,H,S,HD]
    const unsigned short* __restrict__ Vtg,   // V' transposed [bh][d][s]
    const unsigned int* __restrict__ maskg,
    unsigned short* __restrict__ attn_sw)
{
    __shared__ __align__(16) unsigned short Ks[512 * 64];
    __shared__ __align__(16) unsigned short Vs[64 * 512];
    __shared__ __align__(16) unsigned short Ps[8 * 16 * 64];

    const int bh = blockIdx.x >> 2;
    const int qt = blockIdx.x & 3;
    const int b = bh >> 4, h = bh & 15;
    const int tid  = threadIdx.x;
    const int lane = tid & 63;
    const int wid  = tid >> 6;
    const int l15  = lane & 15;
    const int quad = lane >> 4;

    {
        // K' = blend(K) computed inline (kbuf is L2-hot, 64 KB per bh)
        const unsigned short* kbh = kbuf + (size_t)bh * (SS * 64);
        uint4* dst = (uint4*)Ks;
        for (int c = tid; c < 4096; c += 512) {
            int s = c >> 3, cc = c & 7;
            int sm = s ? s - 1 : 0;
            int sp = (s < SS - 1) ? s + 1 : SS - 1;
            F8 k0 = *(const F8*)(kbh + (size_t)s  * 64 + cc * 8);
            F8 km = *(const F8*)(kbh + (size_t)sm * 64 + cc * 8);
            F8 kp = *(const F8*)(kbh + (size_t)sp * 64 + cc * 8);
            F8 o;
#pragma unroll
            for (int j = 0; j < 8; ++j)
                o.h[j] = f2bf(0.75f * bfu(k0.h[j]) + 0.125f * (bfu(km.h[j]) + bfu(kp.h[j])));
            dst[(s << 3) | (cc ^ (s & 7))] = *(uint4*)&o;
        }
        // V' staged from Vtg (vectorized)
        const uint4* srcv = (const uint4*)(Vtg + (size_t)bh * (64 * SS));
        uint4* dstv = (uint4*)Vs;
        for (int c = tid; c < 4096; c += 512) {
            int d = c >> 6, sc = c & 63;
            dstv[(d << 6) | (sc & 56) | ((sc ^ d) & 7)] = srcv[c];
        }
    }
    __syncthreads();

    const int qbase = qt * 128 + wid * 16;
    const int q = qbase + l15;

    F8 qf[2];
    {
        const unsigned short* qrow = qb + ((size_t)bh * SS + q) * 64;
        qf[0] = *(const F8*)(qrow + quad * 8);
        qf[1] = *(const F8*)(qrow + 32 + quad * 8);
    }

    // ---- S^T phase: raw scores
    floatx4 accS[32];
#pragma unroll
    for (int st = 0; st < 32; ++st) {
        int srow = st * 16 + l15;
        const F8 k0 = *(const F8*)(Ks + (((srow << 3) | ( quad      ^ (srow & 7))) << 3));
        const F8 k1 = *(const F8*)(Ks + (((srow << 3) | ((4 + quad) ^ (srow & 7))) << 3));
        floatx4 a = (floatx4){0.f, 0.f, 0.f, 0.f};
        a = __builtin_amdgcn_mfma_f32_16x16x32_bf16(k0.s, qf[0].s, a, 0, 0, 0);
        a = __builtin_amdgcn_mfma_f32_16x16x32_bf16(k1.s, qf[1].s, a, 0, 0, 0);
        accS[st] = a;
    }

    // ---- PV phase: mask*exp fused, P -> swizzled per-wave LDS -> MFMA
    floatx4 accO[4];
#pragma unroll
    for (int dt = 0; dt < 4; ++dt) accO[dt] = (floatx4){0.f, 0.f, 0.f, 0.f};
    float lsum = 0.f;
    unsigned int* Pw = (unsigned int*)Ps + wid * 512;

#pragma unroll
    for (int ch = 0; ch < 8; ++ch) {
        unsigned int mw0 = maskg[(ch * 2) * SS + q];
        unsigned int mw1 = maskg[(ch * 2 + 1) * SS + q];
#pragma unroll
        for (int t = 0; t < 4; ++t) {
            unsigned int mw = (t & 2) ? mw1 : mw0;
            int sbase = (t & 1) * 16 + quad * 4;
            floatx4 a = accS[ch * 4 + t];
            float e0 = ((mw >> (sbase + 0)) & 1u) ? __expf(a[0] * SCALE_F) : 0.f;
            float e1 = ((mw >> (sbase + 1)) & 1u) ? __expf(a[1] * SCALE_F) : 0.f;
            float e2 = ((mw >> (sbase + 2)) & 1u) ? __expf(a[2] * SCALE_F) : 0.f;
            float e3 = ((mw >> (sbase + 3)) & 1u) ? __expf(a[3] * SCALE_F) : 0.f;
            lsum += (e0 + e1) + (e2 + e3);
            unsigned int w0 = (unsigned int)f2bf(e0) | ((unsigned int)f2bf(e1) << 16);
            unsigned int w1 = (unsigned int)f2bf(e2) | ((unsigned int)f2bf(e3) << 16);
            int off0 = t * 8 + quad * 2;
            int off1 = off0 + 1;
            Pw[l15 * 32 + ((((off0 >> 2) ^ (l15 & 7)) << 2) | (off0 & 3))] = w0;
            Pw[l15 * 32 + ((((off1 >> 2) ^ (l15 & 7)) << 2) | (off1 & 3))] = w1;
        }
        F8 pa[2];
#pragma unroll
        for (int ks = 0; ks < 2; ++ks) {
            int ci = ks * 4 + quad;
            pa[ks] = *(const F8*)((const unsigned short*)(Pw + l15 * 32) +
                                  ((ci ^ (l15 & 7)) << 3));
        }
#pragma unroll
        for (int dt = 0; dt < 4; ++dt) {
            int d = dt * 16 + l15;
#pragma unroll
            for (int ks = 0; ks < 2; ++ks) {
                int sc = ch * 8 + ks * 4 + quad;
                const F8 bv = *(const F8*)(Vs + (((d << 6) | (sc & 56) | ((sc ^ d) & 7)) << 3));
                accO[dt] = __builtin_amdgcn_mfma_f32_16x16x32_bf16(pa[ks].s, bv.s, accO[dt], 0, 0, 0);
            }
        }
    }

    lsum += __shfl_xor(lsum, 16);
    lsum += __shfl_xor(lsum, 32);
    float inv = 1.0f / lsum;

    unsigned short* Ow = Ps + wid * 1024;
#pragma unroll
    for (int r = 0; r < 4; ++r) {
        float invr = __shfl(inv, quad * 4 + r);
#pragma unroll
        for (int dt = 0; dt < 4; ++dt)
            Ow[(quad * 4 + r) * 64 + dt * 16 + l15] = f2bf(accO[dt][r] * invr);
    }
#pragma unroll
    for (int i = 0; i < 2; ++i) {
        int ch = i * 64 + lane;
        int qlocal = ch >> 3, j = ch & 7;
        int qq = qt * 128 + wid * 16 + qlocal;
        int mrow = b * SS + qq;
        int mt = mrow >> 7, rr = mrow & 127;
        int kt2 = h * 2 + (j >> 2), c = j & 3;
        size_t gid = (((size_t)(mt * 32 + kt2) * 4 + c) * 128 + rr);
        *(uint4*)(attn_sw + gid * 8) = *(const uint4*)(Ow + qlocal * 64 + j * 8);
    }
}

// ---------------------------------------------------------------------------
extern "C" void kernel_launch(void* const* d_in, const int* in_sizes, int n_in,
                              void* d_out, int out_size, void* d_ws, size_t ws_size,
                              hipStream_t stream)
{
    const float* x     = (const float*)d_in[0];
    const float* w_qkv = (const float*)d_in[1];
    const float* b_qkv = (const float*)d_in[2];
    const float* w_out = (const float*)d_in[3];
    const float* b_out = (const float*)d_in[4];
    const int* routes  = (const int*)d_in[5];

    char* w = (char*)d_ws;
    unsigned short* xb_sw  = (unsigned short*)(w);                 // 4 MB
    unsigned short* wb1_sw = (unsigned short*)(w + (4u  << 20));   // 6 MB
    unsigned short* wb2_sw = (unsigned short*)(w + (10u << 20));   // 2 MB
    unsigned short* qbuf   = (unsigned short*)(w + (12u << 20));   // 4 MB
    unsigned short* kbuf   = (unsigned short*)(w + (16u << 20));   // 4 MB
    unsigned short* vbuf   = (unsigned short*)(w + (20u << 20));   // 4 MB
    unsigned short* Vtg    = (unsigned short*)(w + (24u << 20));   // 4 MB
    unsigned short* attnsw = (unsigned short*)(w + (28u << 20));   // 4 MB
    unsigned int*   maskg  = (unsigned int*)(w + (32u << 20));     // 32 KB

    prep_kernel<<<3074, 256, 0, stream>>>(x, w_qkv, w_out, routes,
                                          xb_sw, wb1_sw, wb2_sw, maskg);

    gemm_qkv<<<dim3(THREE_D / 128, M_ROWS / 128), 256, 0, stream>>>(
        xb_sw, wb1_sw, b_qkv, qbuf, kbuf, vbuf);

    blend_v_kernel<<<256, 256, 0, stream>>>(vbuf, Vtg);

    attn_kernel<<<256, 512, 0, stream>>>(qbuf, kbuf, Vtg, maskg, attnsw);

    gemm_out<<<dim3(DD / 128, M_ROWS / 64), 256, 0, stream>>>(
        attnsw, wb2_sw, b_out, (float*)d_out);
}

// Round 10
// 153.476 us; speedup vs baseline: 1.0561x; 1.0194x over previous
//
#include <hip/hip_runtime.h>
#include <hip/hip_bf16.h>

#define BB 4
#define SS 512
#define DD 1024
#define HH 16
#define KR 64
#define HDIM 64
#define THREE_D 3072
#define M_ROWS 2048
#define SCALE_F 0.125f

typedef __attribute__((ext_vector_type(8))) short short8;
typedef __attribute__((ext_vector_type(4))) float floatx4;

union F8 { short8 s; unsigned int u[4]; unsigned short h[8]; };

__device__ inline float bfu(unsigned short h){ union{unsigned int u; float f;} c; c.u = ((unsigned int)h) << 16; return c.f; }
__device__ inline unsigned short f2bf(float f){
    union{float f; unsigned int u;} c; c.f = f;
    unsigned int u = c.u;
    return (unsigned short)((u + 0x7fffu + ((u >> 16) & 1u)) >> 16);   // RNE
}

#define GLOAD_LDS16(g, l)                                                     \
    __builtin_amdgcn_global_load_lds(                                         \
        (const __attribute__((address_space(1))) unsigned int*)(g),           \
        (__attribute__((address_space(3))) unsigned int*)(l), 16, 0, 0)

// ---------------------------------------------------------------------------
// prep: fused cvtA (x->swizzled bf16) + cvtB(w_qkv) + cvtB(w_out) + mask
// ---------------------------------------------------------------------------
__global__ __launch_bounds__(256) void prep_kernel(
    const float* __restrict__ x, const float* __restrict__ w_qkv,
    const float* __restrict__ w_out, const int* __restrict__ routes,
    unsigned short* __restrict__ xb_sw, unsigned short* __restrict__ wb1_sw,
    unsigned short* __restrict__ wb2_sw, unsigned int* __restrict__ maskg)
{
    const int bx = blockIdx.x;
    const int tid = threadIdx.x;
    if (bx < 1024) {
        int gid = bx * 256 + tid;
        int r  = gid & 127;
        int c  = (gid >> 7) & 3;
        int kt = (gid >> 9) & 31;
        int mt = gid >> 14;
        const float* src = x + ((size_t)(mt * 128 + r)) * 1024 + kt * 32 + c * 8;
        float4 a = *(const float4*)src;
        float4 b = *(const float4*)(src + 4);
        F8 o;
        o.h[0] = f2bf(a.x); o.h[1] = f2bf(a.y); o.h[2] = f2bf(a.z); o.h[3] = f2bf(a.w);
        o.h[4] = f2bf(b.x); o.h[5] = f2bf(b.y); o.h[6] = f2bf(b.z); o.h[7] = f2bf(b.w);
        *(uint4*)(xb_sw + (size_t)gid * 8) = *(uint4*)&o;
    } else if (bx < 3072) {
        const float* w;
        unsigned short* out;
        int gid, N;
        if (bx < 2560) { w = w_qkv; out = wb1_sw; N = THREE_D; gid = (bx - 1024) * 256 + tid; }
        else           { w = w_out; out = wb2_sw; N = DD;      gid = (bx - 2560) * 256 + tid; }
        int r  = gid & 127;
        int c  = (gid >> 7) & 3;
        int kt = (gid >> 9) & 31;
        int nt = gid >> 14;
        int n = nt * 128 + r;
        int kbase = kt * 32 + c * 8;
        F8 o;
#pragma unroll
        for (int j = 0; j < 8; ++j)
            o.h[j] = f2bf(w[(size_t)(kbase + j) * N + n]);
        *(uint4*)(out + (size_t)gid * 8) = *(uint4*)&o;
    } else {
        int q = (bx - 3072) * 256 + tid;
        unsigned int w[16];
#pragma unroll
        for (int i = 0; i < 16; ++i) w[i] = 0u;
        for (int j = 0; j < KR; ++j) {
            int r = routes[q * KR + j];
            if (r <= q) w[r >> 5] |= 1u << (r & 31);
        }
#pragma unroll
        for (int sw = 0; sw < 16; ++sw) maskg[sw * SS + q] = w[sw];
    }
}

// ---------------------------------------------------------------------------
// GEMM1 (QKV): 128x128 tile, BK=64, global_load_lds staging, LDS-assembled
// coalesced bf16 epilogue into q/k/v [B,H,S,HD] bf16.
// XCD-aware swizzle: linear grid of 384; bid&7 = XCD (round-robin dispatch
// heuristic); each XCD owns an 8mt x 6nt super-tile (A 2MB + B 1.5MB < 4MB L2).
// ---------------------------------------------------------------------------
__global__ __launch_bounds__(256) void gemm_qkv(
    const unsigned short* __restrict__ Asw,
    const unsigned short* __restrict__ Bsw,
    const float* __restrict__ bias,
    unsigned short* __restrict__ qb, unsigned short* __restrict__ kb,
    unsigned short* __restrict__ vb)
{
    __shared__ __align__(16) unsigned short Sh[17408];   // 34816 B (union)
    unsigned short* Alds = Sh;
    unsigned short* Blds = Sh + 8192;

    const int tid  = threadIdx.x;
    const int lane = tid & 63;
    const int wid  = tid >> 6;
    const int l15  = lane & 15;
    const int quad = lane >> 4;
    const int wm   = (wid >> 1) * 64;
    const int wn   = (wid & 1) * 64;

    const int bid = blockIdx.x;
    const int xcd = bid & 7;
    const int loc = bid >> 3;                    // 0..47
    const int mt  = (xcd & 1) * 8 + (loc & 7);   // 0..15
    const int nt  = (xcd >> 1) * 6 + (loc >> 3); // 0..23

    const unsigned short* Ak = Asw + (size_t)mt * 131072;
    const unsigned short* Bk = Bsw + (size_t)nt * 131072;

    floatx4 acc[4][4];
#pragma unroll
    for (int i = 0; i < 4; ++i)
#pragma unroll
        for (int j = 0; j < 4; ++j) acc[i][j] = (floatx4){0.f, 0.f, 0.f, 0.f};

    for (int kt2 = 0; kt2 < 16; ++kt2) {
#pragma unroll
        for (int kh = 0; kh < 2; ++kh) {
            const unsigned short* ga = Ak + (kt2 * 2 + kh) * 4096 + wid * 1024 + lane * 8;
            const unsigned short* gb = Bk + (kt2 * 2 + kh) * 4096 + wid * 1024 + lane * 8;
            GLOAD_LDS16(ga,       Alds + kh * 4096 + wid * 1024 + lane * 8);
            GLOAD_LDS16(ga + 512, Alds + kh * 4096 + wid * 1024 + 512 + lane * 8);
            GLOAD_LDS16(gb,       Blds + kh * 4096 + wid * 1024 + lane * 8);
            GLOAD_LDS16(gb + 512, Blds + kh * 4096 + wid * 1024 + 512 + lane * 8);
        }
        __syncthreads();

#pragma unroll
        for (int kh = 0; kh < 2; ++kh) {
            F8 af[4], bf[4];
#pragma unroll
            for (int mi = 0; mi < 4; ++mi)
                af[mi] = *(const F8*)(Alds + kh * 4096 + (size_t)(quad * 128 + wm + mi * 16 + l15) * 8);
#pragma unroll
            for (int ni = 0; ni < 4; ++ni)
                bf[ni] = *(const F8*)(Blds + kh * 4096 + (size_t)(quad * 128 + wn + ni * 16 + l15) * 8);
#pragma unroll
            for (int mi = 0; mi < 4; ++mi)
#pragma unroll
                for (int ni = 0; ni < 4; ++ni)
                    acc[mi][ni] = __builtin_amdgcn_mfma_f32_16x16x32_bf16(
                        af[mi].s, bf[ni].s, acc[mi][ni], 0, 0, 0);
        }
        __syncthreads();
    }

    const int m0 = mt * 128;
    const int n0 = nt * 128;

#pragma unroll
    for (int mi = 0; mi < 4; ++mi) {
#pragma unroll
        for (int ni = 0; ni < 4; ++ni) {
            int col = wn + ni * 16 + l15;
            float bv = bias[n0 + col];
#pragma unroll
            for (int r = 0; r < 4; ++r) {
                int row = wm + mi * 16 + quad * 4 + r;
                Sh[row * 136 + col] = f2bf(acc[mi][ni][r] + bv);
            }
        }
    }
    __syncthreads();

    for (int i = tid; i < 2048; i += 256) {
        int rr = i >> 4, cc = i & 15;
        int grow = m0 + rr, gcol = n0 + cc * 8;
        int b = grow >> 9, s = grow & 511;
        int which = gcol >> 10, rem = gcol & 1023;
        int h = rem >> 6, hd = rem & 63;
        unsigned short* dst = (which == 0) ? qb : (which == 1) ? kb : vb;
        uint4 val = *(const uint4*)(Sh + rr * 136 + cc * 8);
        *(uint4*)(dst + (((size_t)(b * HH + h) * SS) + s) * HDIM + hd) = val;
    }
}

// ---------------------------------------------------------------------------
// GEMM2 (out proj): 64x128 tile, BK=64 -> 256 blocks, fp32 output.
// XCD-aware swizzle: each XCD owns 8mt64 x 4nt (A 1MB + B 1MB).
// ---------------------------------------------------------------------------
__global__ __launch_bounds__(256) void gemm_out(
    const unsigned short* __restrict__ Asw,
    const unsigned short* __restrict__ Bsw,
    const float* __restrict__ bias,
    float* __restrict__ Cout)
{
    __shared__ __align__(16) unsigned short Alds[4096];
    __shared__ __align__(16) unsigned short Blds[8192];

    const int tid  = threadIdx.x;
    const int lane = tid & 63;
    const int wid  = tid >> 6;
    const int l15  = lane & 15;
    const int quad = lane >> 4;

    const int bid  = blockIdx.x;
    const int xcd  = bid & 7;
    const int loc  = bid >> 3;                      // 0..31
    const int mt64 = (xcd & 3) * 8 + (loc & 7);     // 0..31
    const int nt   = (xcd >> 2) * 4 + (loc >> 3);   // 0..7

    const int mt   = mt64 >> 1;
    const int rh   = (mt64 & 1) * 64;
    const int wn   = wid * 32;

    floatx4 acc[4][2];
#pragma unroll
    for (int i = 0; i < 4; ++i)
#pragma unroll
        for (int j = 0; j < 2; ++j) acc[i][j] = (floatx4){0.f, 0.f, 0.f, 0.f};

    for (int kt2 = 0; kt2 < 16; ++kt2) {
#pragma unroll
        for (int kh = 0; kh < 2; ++kh) {
            int kt = kt2 * 2 + kh;
            const unsigned short* ga = Asw + ((size_t)(mt * 32 + kt) * 4 + wid) * 1024 + (rh + lane) * 8;
            const unsigned short* gb = Bsw + (size_t)(nt * 32 + kt) * 4096 + wid * 1024 + lane * 8;
            GLOAD_LDS16(ga,       Alds + kh * 2048 + wid * 512 + lane * 8);
            GLOAD_LDS16(gb,       Blds + kh * 4096 + wid * 1024 + lane * 8);
            GLOAD_LDS16(gb + 512, Blds + kh * 4096 + wid * 1024 + 512 + lane * 8);
        }
        __syncthreads();

#pragma unroll
        for (int kh = 0; kh < 2; ++kh) {
            F8 af[4], bf[2];
#pragma unroll
            for (int mi = 0; mi < 4; ++mi)
                af[mi] = *(const F8*)(Alds + kh * 2048 + (size_t)(quad * 64 + mi * 16 + l15) * 8);
#pragma unroll
            for (int ni = 0; ni < 2; ++ni)
                bf[ni] = *(const F8*)(Blds + kh * 4096 + (size_t)(quad * 128 + wn + ni * 16 + l15) * 8);
#pragma unroll
            for (int mi = 0; mi < 4; ++mi)
#pragma unroll
                for (int ni = 0; ni < 2; ++ni)
                    acc[mi][ni] = __builtin_amdgcn_mfma_f32_16x16x32_bf16(
                        af[mi].s, bf[ni].s, acc[mi][ni], 0, 0, 0);
        }
        __syncthreads();
    }

    const int m0 = mt64 * 64;
    const int n0 = nt * 128;
#pragma unroll
    for (int mi = 0; mi < 4; ++mi) {
#pragma unroll
        for (int ni = 0; ni < 2; ++ni) {
            int col = n0 + wn + ni * 16 + l15;
            float bv = bias[col];
#pragma unroll
            for (int r = 0; r < 4; ++r) {
                int row = m0 + mi * 16 + quad * 4 + r;
                Cout[(size_t)row * DD + col] = acc[mi][ni][r] + bv;
            }
        }
    }
}

// ---------------------------------------------------------------------------
// blend V only: V't[d][s] bf16 (per bh); K' is blended inline in attn.
// ---------------------------------------------------------------------------
__global__ __launch_bounds__(256) void blend_v_kernel(
    const unsigned short* __restrict__ vb, unsigned short* __restrict__ Vtg)
{
    __shared__ float vt[130][65];
    const int bh = blockIdx.x >> 2;
    const int sb = (blockIdx.x & 3) * 128;
    const int tid = threadIdx.x;
    const unsigned short* vbase = vb + (size_t)bh * SS * HDIM;

    for (int i = tid; i < 130 * 8; i += 256) {
        int row = i >> 3, c8 = (i & 7) << 3;
        int s = sb + row - 1; s = s < 0 ? 0 : (s > SS - 1 ? SS - 1 : s);
        F8 vv = *(const F8*)(vbase + (size_t)s * 64 + c8);
#pragma unroll
        for (int j = 0; j < 8; ++j) vt[row][c8 + j] = bfu(vv.h[j]);
    }
    __syncthreads();

    for (int i = tid; i < 64 * 32; i += 256) {
        int d = i >> 5, s4 = (i & 31) << 2;
        ushort4 o;
        o.x = f2bf(0.75f * vt[s4+1][d] + 0.125f * (vt[s4+0][d] + vt[s4+2][d]));
        o.y = f2bf(0.75f * vt[s4+2][d] + 0.125f * (vt[s4+1][d] + vt[s4+3][d]));
        o.z = f2bf(0.75f * vt[s4+3][d] + 0.125f * (vt[s4+2][d] + vt[s4+4][d]));
        o.w = f2bf(0.75f * vt[s4+4][d] + 0.125f * (vt[s4+3][d] + vt[s4+5][d]));
        *(ushort4*)(Vtg + ((size_t)bh * 64 + d) * SS + sb + s4) = o;
    }
}

// ---------------------------------------------------------------------------
// Dense masked flash attention via MFMA; K' blended inline during staging;
// no max pass (scores bounded), mask folded into exp; swizzled-chunk output.
// ---------------------------------------------------------------------------
__global__ __launch_bounds__(512, 2) void attn_kernel(
    const unsigned short* __restrict__ qb,
    const unsigned short* __restrict__ kbuf,  // raw K bf16 [B,H,S,HD]
    const unsigned short* __restrict__ Vtg,   // V' transposed [bh][d][s]
    const unsigned int* __restrict__ maskg,
    unsigned short* __restrict__ attn_sw)
{
    __shared__ __align__(16) unsigned short Ks[512 * 64];
    __shared__ __align__(16) unsigned short Vs[64 * 512];
    __shared__ __align__(16) unsigned short Ps[8 * 16 * 64];

    const int bh = blockIdx.x >> 2;
    const int qt = blockIdx.x & 3;
    const int b = bh >> 4, h = bh & 15;
    const int tid  = threadIdx.x;
    const int lane = tid & 63;
    const int wid  = tid >> 6;
    const int l15  = lane & 15;
    const int quad = lane >> 4;

    {
        const unsigned short* kbh = kbuf + (size_t)bh * (SS * 64);
        uint4* dst = (uint4*)Ks;
        for (int c = tid; c < 4096; c += 512) {
            int s = c >> 3, cc = c & 7;
            int sm = s ? s - 1 : 0;
            int sp = (s < SS - 1) ? s + 1 : SS - 1;
            F8 k0 = *(const F8*)(kbh + (size_t)s  * 64 + cc * 8);
            F8 km = *(const F8*)(kbh + (size_t)sm * 64 + cc * 8);
            F8 kp = *(const F8*)(kbh + (size_t)sp * 64 + cc * 8);
            F8 o;
#pragma unroll
            for (int j = 0; j < 8; ++j)
                o.h[j] = f2bf(0.75f * bfu(k0.h[j]) + 0.125f * (bfu(km.h[j]) + bfu(kp.h[j])));
            dst[(s << 3) | (cc ^ (s & 7))] = *(uint4*)&o;
        }
        const uint4* srcv = (const uint4*)(Vtg + (size_t)bh * (64 * SS));
        uint4* dstv = (uint4*)Vs;
        for (int c = tid; c < 4096; c += 512) {
            int d = c >> 6, sc = c & 63;
            dstv[(d << 6) | (sc & 56) | ((sc ^ d) & 7)] = srcv[c];
        }
    }
    __syncthreads();

    const int qbase = qt * 128 + wid * 16;
    const int q = qbase + l15;

    F8 qf[2];
    {
        const unsigned short* qrow = qb + ((size_t)bh * SS + q) * 64;
        qf[0] = *(const F8*)(qrow + quad * 8);
        qf[1] = *(const F8*)(qrow + 32 + quad * 8);
    }

    floatx4 accS[32];
#pragma unroll
    for (int st = 0; st < 32; ++st) {
        int srow = st * 16 + l15;
        const F8 k0 = *(const F8*)(Ks + (((srow << 3) | ( quad      ^ (srow & 7))) << 3));
        const F8 k1 = *(const F8*)(Ks + (((srow << 3) | ((4 + quad) ^ (srow & 7))) << 3));
        floatx4 a = (floatx4){0.f, 0.f, 0.f, 0.f};
        a = __builtin_amdgcn_mfma_f32_16x16x32_bf16(k0.s, qf[0].s, a, 0, 0, 0);
        a = __builtin_amdgcn_mfma_f32_16x16x32_bf16(k1.s, qf[1].s, a, 0, 0, 0);
        accS[st] = a;
    }

    floatx4 accO[4];
#pragma unroll
    for (int dt = 0; dt < 4; ++dt) accO[dt] = (floatx4){0.f, 0.f, 0.f, 0.f};
    float lsum = 0.f;
    unsigned int* Pw = (unsigned int*)Ps + wid * 512;

#pragma unroll
    for (int ch = 0; ch < 8; ++ch) {
        unsigned int mw0 = maskg[(ch * 2) * SS + q];
        unsigned int mw1 = maskg[(ch * 2 + 1) * SS + q];
#pragma unroll
        for (int t = 0; t < 4; ++t) {
            unsigned int mw = (t & 2) ? mw1 : mw0;
            int sbase = (t & 1) * 16 + quad * 4;
            floatx4 a = accS[ch * 4 + t];
            float e0 = ((mw >> (sbase + 0)) & 1u) ? __expf(a[0] * SCALE_F) : 0.f;
            float e1 = ((mw >> (sbase + 1)) & 1u) ? __expf(a[1] * SCALE_F) : 0.f;
            float e2 = ((mw >> (sbase + 2)) & 1u) ? __expf(a[2] * SCALE_F) : 0.f;
            float e3 = ((mw >> (sbase + 3)) & 1u) ? __expf(a[3] * SCALE_F) : 0.f;
            lsum += (e0 + e1) + (e2 + e3);
            unsigned int w0 = (unsigned int)f2bf(e0) | ((unsigned int)f2bf(e1) << 16);
            unsigned int w1 = (unsigned int)f2bf(e2) | ((unsigned int)f2bf(e3) << 16);
            int off0 = t * 8 + quad * 2;
            int off1 = off0 + 1;
            Pw[l15 * 32 + ((((off0 >> 2) ^ (l15 & 7)) << 2) | (off0 & 3))] = w0;
            Pw[l15 * 32 + ((((off1 >> 2) ^ (l15 & 7)) << 2) | (off1 & 3))] = w1;
        }
        F8 pa[2];
#pragma unroll
        for (int ks = 0; ks < 2; ++ks) {
            int ci = ks * 4 + quad;
            pa[ks] = *(const F8*)((const unsigned short*)(Pw + l15 * 32) +
                                  ((ci ^ (l15 & 7)) << 3));
        }
#pragma unroll
        for (int dt = 0; dt < 4; ++dt) {
            int d = dt * 16 + l15;
#pragma unroll
            for (int ks = 0; ks < 2; ++ks) {
                int sc = ch * 8 + ks * 4 + quad;
                const F8 bv = *(const F8*)(Vs + (((d << 6) | (sc & 56) | ((sc ^ d) & 7)) << 3));
                accO[dt] = __builtin_amdgcn_mfma_f32_16x16x32_bf16(pa[ks].s, bv.s, accO[dt], 0, 0, 0);
            }
        }
    }

    lsum += __shfl_xor(lsum, 16);
    lsum += __shfl_xor(lsum, 32);
    float inv = 1.0f / lsum;

    unsigned short* Ow = Ps + wid * 1024;
#pragma unroll
    for (int r = 0; r < 4; ++r) {
        float invr = __shfl(inv, quad * 4 + r);
#pragma unroll
        for (int dt = 0; dt < 4; ++dt)
            Ow[(quad * 4 + r) * 64 + dt * 16 + l15] = f2bf(accO[dt][r] * invr);
    }
#pragma unroll
    for (int i = 0; i < 2; ++i) {
        int ch = i * 64 + lane;
        int qlocal = ch >> 3, j = ch & 7;
        int qq = qt * 128 + wid * 16 + qlocal;
        int mrow = b * SS + qq;
        int mt = mrow >> 7, rr = mrow & 127;
        int kt2 = h * 2 + (j >> 2), c = j & 3;
        size_t gid = (((size_t)(mt * 32 + kt2) * 4 + c) * 128 + rr);
        *(uint4*)(attn_sw + gid * 8) = *(const uint4*)(Ow + qlocal * 64 + j * 8);
    }
}

// ---------------------------------------------------------------------------
extern "C" void kernel_launch(void* const* d_in, const int* in_sizes, int n_in,
                              void* d_out, int out_size, void* d_ws, size_t ws_size,
                              hipStream_t stream)
{
    const float* x     = (const float*)d_in[0];
    const float* w_qkv = (const float*)d_in[1];
    const float* b_qkv = (const float*)d_in[2];
    const float* w_out = (const float*)d_in[3];
    const float* b_out = (const float*)d_in[4];
    const int* routes  = (const int*)d_in[5];

    char* w = (char*)d_ws;
    unsigned short* xb_sw  = (unsigned short*)(w);                 // 4 MB
    unsigned short* wb1_sw = (unsigned short*)(w + (4u  << 20));   // 6 MB
    unsigned short* wb2_sw = (unsigned short*)(w + (10u << 20));   // 2 MB
    unsigned short* qbuf   = (unsigned short*)(w + (12u << 20));   // 4 MB
    unsigned short* kbuf   = (unsigned short*)(w + (16u << 20));   // 4 MB
    unsigned short* vbuf   = (unsigned short*)(w + (20u << 20));   // 4 MB
    unsigned short* Vtg    = (unsigned short*)(w + (24u << 20));   // 4 MB
    unsigned short* attnsw = (unsigned short*)(w + (28u << 20));   // 4 MB
    unsigned int*   maskg  = (unsigned int*)(w + (32u << 20));     // 32 KB

    prep_kernel<<<3074, 256, 0, stream>>>(x, w_qkv, w_out, routes,
                                          xb_sw, wb1_sw, wb2_sw, maskg);

    gemm_qkv<<<384, 256, 0, stream>>>(xb_sw, wb1_sw, b_qkv, qbuf, kbuf, vbuf);

    blend_v_kernel<<<256, 256, 0, stream>>>(vbuf, Vtg);

    attn_kernel<<<256, 512, 0, stream>>>(qbuf, kbuf, Vtg, maskg, attnsw);

    gemm_out<<<256, 256, 0, stream>>>(attnsw, wb2_sw, b_out, (float*)d_out);
}

// Round 11
// 148.106 us; speedup vs baseline: 1.0943x; 1.0363x over previous
//
#include <hip/hip_runtime.h>
#include <hip/hip_bf16.h>

#define BB 4
#define SS 512
#define DD 1024
#define HH 16
#define KR 64
#define HDIM 64
#define THREE_D 3072
#define M_ROWS 2048
#define SCALE_F 0.125f

typedef __attribute__((ext_vector_type(8))) short short8;
typedef __attribute__((ext_vector_type(4))) float floatx4;

union F8 { short8 s; unsigned int u[4]; unsigned short h[8]; };

__device__ inline float bfu(unsigned short h){ union{unsigned int u; float f;} c; c.u = ((unsigned int)h) << 16; return c.f; }
__device__ inline unsigned short f2bf(float f){
    union{float f; unsigned int u;} c; c.f = f;
    unsigned int u = c.u;
    return (unsigned short)((u + 0x7fffu + ((u >> 16) & 1u)) >> 16);   // RNE
}

#define GLOAD_LDS16(g, l)                                                     \
    __builtin_amdgcn_global_load_lds(                                         \
        (const __attribute__((address_space(1))) unsigned int*)(g),           \
        (__attribute__((address_space(3))) unsigned int*)(l), 16, 0, 0)

// ---------------------------------------------------------------------------
// prep: fused cvtA (x->swizzled bf16) + cvtB(w_qkv) + cvtB(w_out) + mask
// ---------------------------------------------------------------------------
__global__ __launch_bounds__(256) void prep_kernel(
    const float* __restrict__ x, const float* __restrict__ w_qkv,
    const float* __restrict__ w_out, const int* __restrict__ routes,
    unsigned short* __restrict__ xb_sw, unsigned short* __restrict__ wb1_sw,
    unsigned short* __restrict__ wb2_sw, unsigned int* __restrict__ maskg)
{
    const int bx = blockIdx.x;
    const int tid = threadIdx.x;
    if (bx < 1024) {
        int gid = bx * 256 + tid;
        int r  = gid & 127;
        int c  = (gid >> 7) & 3;
        int kt = (gid >> 9) & 31;
        int mt = gid >> 14;
        const float* src = x + ((size_t)(mt * 128 + r)) * 1024 + kt * 32 + c * 8;
        float4 a = *(const float4*)src;
        float4 b = *(const float4*)(src + 4);
        F8 o;
        o.h[0] = f2bf(a.x); o.h[1] = f2bf(a.y); o.h[2] = f2bf(a.z); o.h[3] = f2bf(a.w);
        o.h[4] = f2bf(b.x); o.h[5] = f2bf(b.y); o.h[6] = f2bf(b.z); o.h[7] = f2bf(b.w);
        *(uint4*)(xb_sw + (size_t)gid * 8) = *(uint4*)&o;
    } else if (bx < 3072) {
        const float* w;
        unsigned short* out;
        int gid, N;
        if (bx < 2560) { w = w_qkv; out = wb1_sw; N = THREE_D; gid = (bx - 1024) * 256 + tid; }
        else           { w = w_out; out = wb2_sw; N = DD;      gid = (bx - 2560) * 256 + tid; }
        int r  = gid & 127;
        int c  = (gid >> 7) & 3;
        int kt = (gid >> 9) & 31;
        int nt = gid >> 14;
        int n = nt * 128 + r;
        int kbase = kt * 32 + c * 8;
        F8 o;
#pragma unroll
        for (int j = 0; j < 8; ++j)
            o.h[j] = f2bf(w[(size_t)(kbase + j) * N + n]);
        *(uint4*)(out + (size_t)gid * 8) = *(uint4*)&o;
    } else {
        int q = (bx - 3072) * 256 + tid;
        unsigned int w[16];
#pragma unroll
        for (int i = 0; i < 16; ++i) w[i] = 0u;
        for (int j = 0; j < KR; ++j) {
            int r = routes[q * KR + j];
            if (r <= q) w[r >> 5] |= 1u << (r & 31);
        }
#pragma unroll
        for (int sw = 0; sw < 16; ++sw) maskg[sw * SS + q] = w[sw];
    }
}

// ---------------------------------------------------------------------------
// GEMM1 (QKV): 64x128 tile, BK=64 -> 768 blocks = exactly 3/CU (drain overlap).
// 4 waves, each 64m x 32n (4m x 2n accs). LDS-assembled bf16 epilogue.
// XCD map: 8 mt64 x 12 nt per XCD (A 1MB + B 3MB = 4MB L2).
// ---------------------------------------------------------------------------
__global__ __launch_bounds__(256) void gemm_qkv(
    const unsigned short* __restrict__ Asw,   // [mt128][kt][c][r128]
    const unsigned short* __restrict__ Bsw,   // [nt128][kt][c][r128]
    const float* __restrict__ bias,
    unsigned short* __restrict__ qb, unsigned short* __restrict__ kb,
    unsigned short* __restrict__ vb)
{
    __shared__ __align__(16) unsigned short Sh[12288];   // 24576 B (union w/ epi)
    unsigned short* Alds = Sh;            // 2 kh x 2048
    unsigned short* Blds = Sh + 4096;     // 2 kh x 4096

    const int tid  = threadIdx.x;
    const int lane = tid & 63;
    const int wid  = tid >> 6;
    const int l15  = lane & 15;
    const int quad = lane >> 4;

    const int bid  = blockIdx.x;
    const int xcd  = bid & 7;
    const int loc  = bid >> 3;                       // 0..95
    const int mt64 = (xcd & 3) * 8 + (loc & 7);      // 0..31
    const int nt   = (xcd >> 2) * 12 + (loc >> 3);   // 0..23

    const int mt = mt64 >> 1;
    const int rh = (mt64 & 1) * 64;
    const int wn = wid * 32;

    floatx4 acc[4][2];
#pragma unroll
    for (int i = 0; i < 4; ++i)
#pragma unroll
        for (int j = 0; j < 2; ++j) acc[i][j] = (floatx4){0.f, 0.f, 0.f, 0.f};

    for (int kt2 = 0; kt2 < 16; ++kt2) {
#pragma unroll
        for (int kh = 0; kh < 2; ++kh) {
            int kt = kt2 * 2 + kh;
            const unsigned short* ga = Asw + ((size_t)(mt * 32 + kt) * 4 + wid) * 1024 + (rh + lane) * 8;
            const unsigned short* gb = Bsw + (size_t)(nt * 32 + kt) * 4096 + wid * 1024 + lane * 8;
            GLOAD_LDS16(ga,       Alds + kh * 2048 + wid * 512 + lane * 8);
            GLOAD_LDS16(gb,       Blds + kh * 4096 + wid * 1024 + lane * 8);
            GLOAD_LDS16(gb + 512, Blds + kh * 4096 + wid * 1024 + 512 + lane * 8);
        }
        __syncthreads();

#pragma unroll
        for (int kh = 0; kh < 2; ++kh) {
            F8 af[4], bf[2];
#pragma unroll
            for (int mi = 0; mi < 4; ++mi)
                af[mi] = *(const F8*)(Alds + kh * 2048 + (size_t)(quad * 64 + mi * 16 + l15) * 8);
#pragma unroll
            for (int ni = 0; ni < 2; ++ni)
                bf[ni] = *(const F8*)(Blds + kh * 4096 + (size_t)(quad * 128 + wn + ni * 16 + l15) * 8);
#pragma unroll
            for (int mi = 0; mi < 4; ++mi)
#pragma unroll
                for (int ni = 0; ni < 2; ++ni)
                    acc[mi][ni] = __builtin_amdgcn_mfma_f32_16x16x32_bf16(
                        af[mi].s, bf[ni].s, acc[mi][ni], 0, 0, 0);
        }
        __syncthreads();
    }

    const int m0 = mt64 * 64;
    const int n0 = nt * 128;

    // phase 1: acc -> bf16 64x128 tile in LDS (stride 136)
#pragma unroll
    for (int mi = 0; mi < 4; ++mi) {
#pragma unroll
        for (int ni = 0; ni < 2; ++ni) {
            int col = wn + ni * 16 + l15;
            float bv = bias[n0 + col];
#pragma unroll
            for (int r = 0; r < 4; ++r) {
                int row = mi * 16 + quad * 4 + r;
                Sh[row * 136 + col] = f2bf(acc[mi][ni][r] + bv);
            }
        }
    }
    __syncthreads();

    // phase 2: coalesced 16B stores into q/k/v
    for (int i = tid; i < 1024; i += 256) {
        int rr = i >> 4, cc = i & 15;
        int grow = m0 + rr, gcol = n0 + cc * 8;
        int b = grow >> 9, s = grow & 511;
        int which = gcol >> 10, rem = gcol & 1023;
        int h = rem >> 6, hd = rem & 63;
        unsigned short* dst = (which == 0) ? qb : (which == 1) ? kb : vb;
        uint4 val = *(const uint4*)(Sh + rr * 136 + cc * 8);
        *(uint4*)(dst + (((size_t)(b * HH + h) * SS) + s) * HDIM + hd) = val;
    }
}

// ---------------------------------------------------------------------------
// GEMM2 (out proj): 64x64 tile, BK=64 -> 512 blocks = 2/CU. Waves 2x2 of
// 32x32 (acc 2x2). fp32 output. XCD map: 8 mt64 x 8 nt64 per XCD (2MB).
// ---------------------------------------------------------------------------
__global__ __launch_bounds__(256) void gemm_out(
    const unsigned short* __restrict__ Asw,   // [mt128][kt][c][r128]
    const unsigned short* __restrict__ Bsw,   // [nt128][kt][c][r128]
    const float* __restrict__ bias,
    float* __restrict__ Cout)
{
    __shared__ __align__(16) unsigned short Alds[4096];  // 2 kh x 2048
    __shared__ __align__(16) unsigned short Blds[4096];

    const int tid  = threadIdx.x;
    const int lane = tid & 63;
    const int wid  = tid >> 6;
    const int l15  = lane & 15;
    const int quad = lane >> 4;

    const int bid  = blockIdx.x;
    const int xcd  = bid & 7;
    const int loc  = bid >> 3;                       // 0..63
    const int mt64 = (xcd & 3) * 8 + (loc & 7);      // 0..31
    const int nt64 = (xcd >> 2) * 8 + (loc >> 3);    // 0..15

    const int mt  = mt64 >> 1;
    const int rh  = (mt64 & 1) * 64;
    const int ntB = nt64 >> 1;
    const int rhB = (nt64 & 1) * 64;
    const int wm  = (wid >> 1) * 32;
    const int wn  = (wid & 1) * 32;

    floatx4 acc[2][2];
#pragma unroll
    for (int i = 0; i < 2; ++i)
#pragma unroll
        for (int j = 0; j < 2; ++j) acc[i][j] = (floatx4){0.f, 0.f, 0.f, 0.f};

    for (int kt2 = 0; kt2 < 16; ++kt2) {
#pragma unroll
        for (int kh = 0; kh < 2; ++kh) {
            int kt = kt2 * 2 + kh;
            const unsigned short* ga = Asw + ((size_t)(mt  * 32 + kt) * 4 + wid) * 1024 + (rh  + lane) * 8;
            const unsigned short* gb = Bsw + ((size_t)(ntB * 32 + kt) * 4 + wid) * 1024 + (rhB + lane) * 8;
            GLOAD_LDS16(ga, Alds + kh * 2048 + wid * 512 + lane * 8);
            GLOAD_LDS16(gb, Blds + kh * 2048 + wid * 512 + lane * 8);
        }
        __syncthreads();

#pragma unroll
        for (int kh = 0; kh < 2; ++kh) {
            F8 af[2], bf[2];
#pragma unroll
            for (int mi = 0; mi < 2; ++mi)
                af[mi] = *(const F8*)(Alds + kh * 2048 + (size_t)(quad * 64 + wm + mi * 16 + l15) * 8);
#pragma unroll
            for (int ni = 0; ni < 2; ++ni)
                bf[ni] = *(const F8*)(Blds + kh * 2048 + (size_t)(quad * 64 + wn + ni * 16 + l15) * 8);
#pragma unroll
            for (int mi = 0; mi < 2; ++mi)
#pragma unroll
                for (int ni = 0; ni < 2; ++ni)
                    acc[mi][ni] = __builtin_amdgcn_mfma_f32_16x16x32_bf16(
                        af[mi].s, bf[ni].s, acc[mi][ni], 0, 0, 0);
        }
        __syncthreads();
    }

    const int m0 = mt64 * 64;
    const int n0 = nt64 * 64;
#pragma unroll
    for (int mi = 0; mi < 2; ++mi) {
#pragma unroll
        for (int ni = 0; ni < 2; ++ni) {
            int col = n0 + wn + ni * 16 + l15;
            float bv = bias[col];
#pragma unroll
            for (int r = 0; r < 4; ++r) {
                int row = m0 + wm + mi * 16 + quad * 4 + r;
                Cout[(size_t)row * DD + col] = acc[mi][ni][r] + bv;
            }
        }
    }
}

// ---------------------------------------------------------------------------
// blend V only: V't[d][s] bf16 (per bh); K' is blended inline in attn.
// ---------------------------------------------------------------------------
__global__ __launch_bounds__(256) void blend_v_kernel(
    const unsigned short* __restrict__ vb, unsigned short* __restrict__ Vtg)
{
    __shared__ float vt[130][65];
    const int bh = blockIdx.x >> 2;
    const int sb = (blockIdx.x & 3) * 128;
    const int tid = threadIdx.x;
    const unsigned short* vbase = vb + (size_t)bh * SS * HDIM;

    for (int i = tid; i < 130 * 8; i += 256) {
        int row = i >> 3, c8 = (i & 7) << 3;
        int s = sb + row - 1; s = s < 0 ? 0 : (s > SS - 1 ? SS - 1 : s);
        F8 vv = *(const F8*)(vbase + (size_t)s * 64 + c8);
#pragma unroll
        for (int j = 0; j < 8; ++j) vt[row][c8 + j] = bfu(vv.h[j]);
    }
    __syncthreads();

    for (int i = tid; i < 64 * 32; i += 256) {
        int d = i >> 5, s4 = (i & 31) << 2;
        ushort4 o;
        o.x = f2bf(0.75f * vt[s4+1][d] + 0.125f * (vt[s4+0][d] + vt[s4+2][d]));
        o.y = f2bf(0.75f * vt[s4+2][d] + 0.125f * (vt[s4+1][d] + vt[s4+3][d]));
        o.z = f2bf(0.75f * vt[s4+3][d] + 0.125f * (vt[s4+2][d] + vt[s4+4][d]));
        o.w = f2bf(0.75f * vt[s4+4][d] + 0.125f * (vt[s4+3][d] + vt[s4+5][d]));
        *(ushort4*)(Vtg + ((size_t)bh * 64 + d) * SS + sb + s4) = o;
    }
}

// ---------------------------------------------------------------------------
// Dense masked flash attention via MFMA; K' blended inline during staging;
// no max pass (scores bounded), mask folded into exp; swizzled-chunk output.
// ---------------------------------------------------------------------------
__global__ __launch_bounds__(512, 2) void attn_kernel(
    const unsigned short* __restrict__ qb,
    const unsigned short* __restrict__ kbuf,  // raw K bf16 [B,H,S,HD]
    const unsigned short* __restrict__ Vtg,   // V' transposed [bh][d][s]
    const unsigned int* __restrict__ maskg,
    unsigned short* __restrict__ attn_sw)
{
    __shared__ __align__(16) unsigned short Ks[512 * 64];
    __shared__ __align__(16) unsigned short Vs[64 * 512];
    __shared__ __align__(16) unsigned short Ps[8 * 16 * 64];

    const int bh = blockIdx.x >> 2;
    const int qt = blockIdx.x & 3;
    const int b = bh >> 4, h = bh & 15;
    const int tid  = threadIdx.x;
    const int lane = tid & 63;
    const int wid  = tid >> 6;
    const int l15  = lane & 15;
    const int quad = lane >> 4;

    {
        const unsigned short* kbh = kbuf + (size_t)bh * (SS * 64);
        uint4* dst = (uint4*)Ks;
        for (int c = tid; c < 4096; c += 512) {
            int s = c >> 3, cc = c & 7;
            int sm = s ? s - 1 : 0;
            int sp = (s < SS - 1) ? s + 1 : SS - 1;
            F8 k0 = *(const F8*)(kbh + (size_t)s  * 64 + cc * 8);
            F8 km = *(const F8*)(kbh + (size_t)sm * 64 + cc * 8);
            F8 kp = *(const F8*)(kbh + (size_t)sp * 64 + cc * 8);
            F8 o;
#pragma unroll
            for (int j = 0; j < 8; ++j)
                o.h[j] = f2bf(0.75f * bfu(k0.h[j]) + 0.125f * (bfu(km.h[j]) + bfu(kp.h[j])));
            dst[(s << 3) | (cc ^ (s & 7))] = *(uint4*)&o;
        }
        const uint4* srcv = (const uint4*)(Vtg + (size_t)bh * (64 * SS));
        uint4* dstv = (uint4*)Vs;
        for (int c = tid; c < 4096; c += 512) {
            int d = c >> 6, sc = c & 63;
            dstv[(d << 6) | (sc & 56) | ((sc ^ d) & 7)] = srcv[c];
        }
    }
    __syncthreads();

    const int qbase = qt * 128 + wid * 16;
    const int q = qbase + l15;

    F8 qf[2];
    {
        const unsigned short* qrow = qb + ((size_t)bh * SS + q) * 64;
        qf[0] = *(const F8*)(qrow + quad * 8);
        qf[1] = *(const F8*)(qrow + 32 + quad * 8);
    }

    floatx4 accS[32];
#pragma unroll
    for (int st = 0; st < 32; ++st) {
        int srow = st * 16 + l15;
        const F8 k0 = *(const F8*)(Ks + (((srow << 3) | ( quad      ^ (srow & 7))) << 3));
        const F8 k1 = *(const F8*)(Ks + (((srow << 3) | ((4 + quad) ^ (srow & 7))) << 3));
        floatx4 a = (floatx4){0.f, 0.f, 0.f, 0.f};
        a = __builtin_amdgcn_mfma_f32_16x16x32_bf16(k0.s, qf[0].s, a, 0, 0, 0);
        a = __builtin_amdgcn_mfma_f32_16x16x32_bf16(k1.s, qf[1].s, a, 0, 0, 0);
        accS[st] = a;
    }

    floatx4 accO[4];
#pragma unroll
    for (int dt = 0; dt < 4; ++dt) accO[dt] = (floatx4){0.f, 0.f, 0.f, 0.f};
    float lsum = 0.f;
    unsigned int* Pw = (unsigned int*)Ps + wid * 512;

#pragma unroll
    for (int ch = 0; ch < 8; ++ch) {
        unsigned int mw0 = maskg[(ch * 2) * SS + q];
        unsigned int mw1 = maskg[(ch * 2 + 1) * SS + q];
#pragma unroll
        for (int t = 0; t < 4; ++t) {
            unsigned int mw = (t & 2) ? mw1 : mw0;
            int sbase = (t & 1) * 16 + quad * 4;
            floatx4 a = accS[ch * 4 + t];
            float e0 = ((mw >> (sbase + 0)) & 1u) ? __expf(a[0] * SCALE_F) : 0.f;
            float e1 = ((mw >> (sbase + 1)) & 1u) ? __expf(a[1] * SCALE_F) : 0.f;
            float e2 = ((mw >> (sbase + 2)) & 1u) ? __expf(a[2] * SCALE_F) : 0.f;
            float e3 = ((mw >> (sbase + 3)) & 1u) ? __expf(a[3] * SCALE_F) : 0.f;
            lsum += (e0 + e1) + (e2 + e3);
            unsigned int w0 = (unsigned int)f2bf(e0) | ((unsigned int)f2bf(e1) << 16);
            unsigned int w1 = (unsigned int)f2bf(e2) | ((unsigned int)f2bf(e3) << 16);
            int off0 = t * 8 + quad * 2;
            int off1 = off0 + 1;
            Pw[l15 * 32 + ((((off0 >> 2) ^ (l15 & 7)) << 2) | (off0 & 3))] = w0;
            Pw[l15 * 32 + ((((off1 >> 2) ^ (l15 & 7)) << 2) | (off1 & 3))] = w1;
        }
        F8 pa[2];
#pragma unroll
        for (int ks = 0; ks < 2; ++ks) {
            int ci = ks * 4 + quad;
            pa[ks] = *(const F8*)((const unsigned short*)(Pw + l15 * 32) +
                                  ((ci ^ (l15 & 7)) << 3));
        }
#pragma unroll
        for (int dt = 0; dt < 4; ++dt) {
            int d = dt * 16 + l15;
#pragma unroll
            for (int ks = 0; ks < 2; ++ks) {
                int sc = ch * 8 + ks * 4 + quad;
                const F8 bv = *(const F8*)(Vs + (((d << 6) | (sc & 56) | ((sc ^ d) & 7)) << 3));
                accO[dt] = __builtin_amdgcn_mfma_f32_16x16x32_bf16(pa[ks].s, bv.s, accO[dt], 0, 0, 0);
            }
        }
    }

    lsum += __shfl_xor(lsum, 16);
    lsum += __shfl_xor(lsum, 32);
    float inv = 1.0f / lsum;

    unsigned short* Ow = Ps + wid * 1024;
#pragma unroll
    for (int r = 0; r < 4; ++r) {
        float invr = __shfl(inv, quad * 4 + r);
#pragma unroll
        for (int dt = 0; dt < 4; ++dt)
            Ow[(quad * 4 + r) * 64 + dt * 16 + l15] = f2bf(accO[dt][r] * invr);
    }
#pragma unroll
    for (int i = 0; i < 2; ++i) {
        int ch = i * 64 + lane;
        int qlocal = ch >> 3, j = ch & 7;
        int qq = qt * 128 + wid * 16 + qlocal;
        int mrow = b * SS + qq;
        int mt = mrow >> 7, rr = mrow & 127;
        int kt2 = h * 2 + (j >> 2), c = j & 3;
        size_t gid = (((size_t)(mt * 32 + kt2) * 4 + c) * 128 + rr);
        *(uint4*)(attn_sw + gid * 8) = *(const uint4*)(Ow + qlocal * 64 + j * 8);
    }
}

// ---------------------------------------------------------------------------
extern "C" void kernel_launch(void* const* d_in, const int* in_sizes, int n_in,
                              void* d_out, int out_size, void* d_ws, size_t ws_size,
                              hipStream_t stream)
{
    const float* x     = (const float*)d_in[0];
    const float* w_qkv = (const float*)d_in[1];
    const float* b_qkv = (const float*)d_in[2];
    const float* w_out = (const float*)d_in[3];
    const float* b_out = (const float*)d_in[4];
    const int* routes  = (const int*)d_in[5];

    char* w = (char*)d_ws;
    unsigned short* xb_sw  = (unsigned short*)(w);                 // 4 MB
    unsigned short* wb1_sw = (unsigned short*)(w + (4u  << 20));   // 6 MB
    unsigned short* wb2_sw = (unsigned short*)(w + (10u << 20));   // 2 MB
    unsigned short* qbuf   = (unsigned short*)(w + (12u << 20));   // 4 MB
    unsigned short* kbuf   = (unsigned short*)(w + (16u << 20));   // 4 MB
    unsigned short* vbuf   = (unsigned short*)(w + (20u << 20));   // 4 MB
    unsigned short* Vtg    = (unsigned short*)(w + (24u << 20));   // 4 MB
    unsigned short* attnsw = (unsigned short*)(w + (28u << 20));   // 4 MB
    unsigned int*   maskg  = (unsigned int*)(w + (32u << 20));     // 32 KB

    prep_kernel<<<3074, 256, 0, stream>>>(x, w_qkv, w_out, routes,
                                          xb_sw, wb1_sw, wb2_sw, maskg);

    gemm_qkv<<<768, 256, 0, stream>>>(xb_sw, wb1_sw, b_qkv, qbuf, kbuf, vbuf);

    blend_v_kernel<<<256, 256, 0, stream>>>(vbuf, Vtg);

    attn_kernel<<<256, 512, 0, stream>>>(qbuf, kbuf, Vtg, maskg, attnsw);

    gemm_out<<<512, 256, 0, stream>>>(attnsw, wb2_sw, b_out, (float*)d_out);
}

// Round 12
// 145.437 us; speedup vs baseline: 1.1144x; 1.0184x over previous
//
#include <hip/hip_runtime.h>
#include <hip/hip_bf16.h>

#define BB 4
#define SS 512
#define DD 1024
#define HH 16
#define KR 64
#define HDIM 64
#define THREE_D 3072
#define M_ROWS 2048
#define SCALE_F 0.125f

typedef __attribute__((ext_vector_type(8))) short short8;
typedef __attribute__((ext_vector_type(4))) float floatx4;

union F8 { short8 s; unsigned int u[4]; unsigned short h[8]; };

__device__ inline float bfu(unsigned short h){ union{unsigned int u; float f;} c; c.u = ((unsigned int)h) << 16; return c.f; }
__device__ inline unsigned short f2bf(float f){
    union{float f; unsigned int u;} c; c.f = f;
    unsigned int u = c.u;
    return (unsigned short)((u + 0x7fffu + ((u >> 16) & 1u)) >> 16);   // RNE
}

#define GLOAD_LDS16(g, l)                                                     \
    __builtin_amdgcn_global_load_lds(                                         \
        (const __attribute__((address_space(1))) unsigned int*)(g),           \
        (__attribute__((address_space(3))) unsigned int*)(l), 16, 0, 0)

// ---------------------------------------------------------------------------
// prep: fused cvtA (x->swizzled bf16) + cvtB(w_qkv) + cvtB(w_out) + mask
// ---------------------------------------------------------------------------
__global__ __launch_bounds__(256) void prep_kernel(
    const float* __restrict__ x, const float* __restrict__ w_qkv,
    const float* __restrict__ w_out, const int* __restrict__ routes,
    unsigned short* __restrict__ xb_sw, unsigned short* __restrict__ wb1_sw,
    unsigned short* __restrict__ wb2_sw, unsigned int* __restrict__ maskg)
{
    const int bx = blockIdx.x;
    const int tid = threadIdx.x;
    if (bx < 1024) {
        int gid = bx * 256 + tid;
        int r  = gid & 127;
        int c  = (gid >> 7) & 3;
        int kt = (gid >> 9) & 31;
        int mt = gid >> 14;
        const float* src = x + ((size_t)(mt * 128 + r)) * 1024 + kt * 32 + c * 8;
        float4 a = *(const float4*)src;
        float4 b = *(const float4*)(src + 4);
        F8 o;
        o.h[0] = f2bf(a.x); o.h[1] = f2bf(a.y); o.h[2] = f2bf(a.z); o.h[3] = f2bf(a.w);
        o.h[4] = f2bf(b.x); o.h[5] = f2bf(b.y); o.h[6] = f2bf(b.z); o.h[7] = f2bf(b.w);
        *(uint4*)(xb_sw + (size_t)gid * 8) = *(uint4*)&o;
    } else if (bx < 3072) {
        const float* w;
        unsigned short* out;
        int gid, N;
        if (bx < 2560) { w = w_qkv; out = wb1_sw; N = THREE_D; gid = (bx - 1024) * 256 + tid; }
        else           { w = w_out; out = wb2_sw; N = DD;      gid = (bx - 2560) * 256 + tid; }
        int r  = gid & 127;
        int c  = (gid >> 7) & 3;
        int kt = (gid >> 9) & 31;
        int nt = gid >> 14;
        int n = nt * 128 + r;
        int kbase = kt * 32 + c * 8;
        F8 o;
#pragma unroll
        for (int j = 0; j < 8; ++j)
            o.h[j] = f2bf(w[(size_t)(kbase + j) * N + n]);
        *(uint4*)(out + (size_t)gid * 8) = *(uint4*)&o;
    } else {
        int q = (bx - 3072) * 256 + tid;
        unsigned int w[16];
#pragma unroll
        for (int i = 0; i < 16; ++i) w[i] = 0u;
        for (int j = 0; j < KR; ++j) {
            int r = routes[q * KR + j];
            if (r <= q) w[r >> 5] |= 1u << (r & 31);
        }
#pragma unroll
        for (int sw = 0; sw < 16; ++sw) maskg[sw * SS + q] = w[sw];
    }
}

// ---------------------------------------------------------------------------
// GEMM1 (QKV): 64x128 tile, BK=64 -> 768 blocks = 3/CU. (unchanged from R11)
// ---------------------------------------------------------------------------
__global__ __launch_bounds__(256) void gemm_qkv(
    const unsigned short* __restrict__ Asw,
    const unsigned short* __restrict__ Bsw,
    const float* __restrict__ bias,
    unsigned short* __restrict__ qb, unsigned short* __restrict__ kb,
    unsigned short* __restrict__ vb)
{
    __shared__ __align__(16) unsigned short Sh[12288];
    unsigned short* Alds = Sh;
    unsigned short* Blds = Sh + 4096;

    const int tid  = threadIdx.x;
    const int lane = tid & 63;
    const int wid  = tid >> 6;
    const int l15  = lane & 15;
    const int quad = lane >> 4;

    const int bid  = blockIdx.x;
    const int xcd  = bid & 7;
    const int loc  = bid >> 3;
    const int mt64 = (xcd & 3) * 8 + (loc & 7);
    const int nt   = (xcd >> 2) * 12 + (loc >> 3);

    const int mt = mt64 >> 1;
    const int rh = (mt64 & 1) * 64;
    const int wn = wid * 32;

    floatx4 acc[4][2];
#pragma unroll
    for (int i = 0; i < 4; ++i)
#pragma unroll
        for (int j = 0; j < 2; ++j) acc[i][j] = (floatx4){0.f, 0.f, 0.f, 0.f};

    for (int kt2 = 0; kt2 < 16; ++kt2) {
#pragma unroll
        for (int kh = 0; kh < 2; ++kh) {
            int kt = kt2 * 2 + kh;
            const unsigned short* ga = Asw + ((size_t)(mt * 32 + kt) * 4 + wid) * 1024 + (rh + lane) * 8;
            const unsigned short* gb = Bsw + (size_t)(nt * 32 + kt) * 4096 + wid * 1024 + lane * 8;
            GLOAD_LDS16(ga,       Alds + kh * 2048 + wid * 512 + lane * 8);
            GLOAD_LDS16(gb,       Blds + kh * 4096 + wid * 1024 + lane * 8);
            GLOAD_LDS16(gb + 512, Blds + kh * 4096 + wid * 1024 + 512 + lane * 8);
        }
        __syncthreads();

#pragma unroll
        for (int kh = 0; kh < 2; ++kh) {
            F8 af[4], bf[2];
#pragma unroll
            for (int mi = 0; mi < 4; ++mi)
                af[mi] = *(const F8*)(Alds + kh * 2048 + (size_t)(quad * 64 + mi * 16 + l15) * 8);
#pragma unroll
            for (int ni = 0; ni < 2; ++ni)
                bf[ni] = *(const F8*)(Blds + kh * 4096 + (size_t)(quad * 128 + wn + ni * 16 + l15) * 8);
#pragma unroll
            for (int mi = 0; mi < 4; ++mi)
#pragma unroll
                for (int ni = 0; ni < 2; ++ni)
                    acc[mi][ni] = __builtin_amdgcn_mfma_f32_16x16x32_bf16(
                        af[mi].s, bf[ni].s, acc[mi][ni], 0, 0, 0);
        }
        __syncthreads();
    }

    const int m0 = mt64 * 64;
    const int n0 = nt * 128;

#pragma unroll
    for (int mi = 0; mi < 4; ++mi) {
#pragma unroll
        for (int ni = 0; ni < 2; ++ni) {
            int col = wn + ni * 16 + l15;
            float bv = bias[n0 + col];
#pragma unroll
            for (int r = 0; r < 4; ++r) {
                int row = mi * 16 + quad * 4 + r;
                Sh[row * 136 + col] = f2bf(acc[mi][ni][r] + bv);
            }
        }
    }
    __syncthreads();

    for (int i = tid; i < 1024; i += 256) {
        int rr = i >> 4, cc = i & 15;
        int grow = m0 + rr, gcol = n0 + cc * 8;
        int b = grow >> 9, s = grow & 511;
        int which = gcol >> 10, rem = gcol & 1023;
        int h = rem >> 6, hd = rem & 63;
        unsigned short* dst = (which == 0) ? qb : (which == 1) ? kb : vb;
        uint4 val = *(const uint4*)(Sh + rr * 136 + cc * 8);
        *(uint4*)(dst + (((size_t)(b * HH + h) * SS) + s) * HDIM + hd) = val;
    }
}

// ---------------------------------------------------------------------------
// GEMM2 (out proj): 64x64 tile, BK=64 -> 512 blocks = 2/CU. (unchanged)
// ---------------------------------------------------------------------------
__global__ __launch_bounds__(256) void gemm_out(
    const unsigned short* __restrict__ Asw,
    const unsigned short* __restrict__ Bsw,
    const float* __restrict__ bias,
    float* __restrict__ Cout)
{
    __shared__ __align__(16) unsigned short Alds[4096];
    __shared__ __align__(16) unsigned short Blds[4096];

    const int tid  = threadIdx.x;
    const int lane = tid & 63;
    const int wid  = tid >> 6;
    const int l15  = lane & 15;
    const int quad = lane >> 4;

    const int bid  = blockIdx.x;
    const int xcd  = bid & 7;
    const int loc  = bid >> 3;
    const int mt64 = (xcd & 3) * 8 + (loc & 7);
    const int nt64 = (xcd >> 2) * 8 + (loc >> 3);

    const int mt  = mt64 >> 1;
    const int rh  = (mt64 & 1) * 64;
    const int ntB = nt64 >> 1;
    const int rhB = (nt64 & 1) * 64;
    const int wm  = (wid >> 1) * 32;
    const int wn  = (wid & 1) * 32;

    floatx4 acc[2][2];
#pragma unroll
    for (int i = 0; i < 2; ++i)
#pragma unroll
        for (int j = 0; j < 2; ++j) acc[i][j] = (floatx4){0.f, 0.f, 0.f, 0.f};

    for (int kt2 = 0; kt2 < 16; ++kt2) {
#pragma unroll
        for (int kh = 0; kh < 2; ++kh) {
            int kt = kt2 * 2 + kh;
            const unsigned short* ga = Asw + ((size_t)(mt  * 32 + kt) * 4 + wid) * 1024 + (rh  + lane) * 8;
            const unsigned short* gb = Bsw + ((size_t)(ntB * 32 + kt) * 4 + wid) * 1024 + (rhB + lane) * 8;
            GLOAD_LDS16(ga, Alds + kh * 2048 + wid * 512 + lane * 8);
            GLOAD_LDS16(gb, Blds + kh * 2048 + wid * 512 + lane * 8);
        }
        __syncthreads();

#pragma unroll
        for (int kh = 0; kh < 2; ++kh) {
            F8 af[2], bf[2];
#pragma unroll
            for (int mi = 0; mi < 2; ++mi)
                af[mi] = *(const F8*)(Alds + kh * 2048 + (size_t)(quad * 64 + wm + mi * 16 + l15) * 8);
#pragma unroll
            for (int ni = 0; ni < 2; ++ni)
                bf[ni] = *(const F8*)(Blds + kh * 2048 + (size_t)(quad * 64 + wn + ni * 16 + l15) * 8);
#pragma unroll
            for (int mi = 0; mi < 2; ++mi)
#pragma unroll
                for (int ni = 0; ni < 2; ++ni)
                    acc[mi][ni] = __builtin_amdgcn_mfma_f32_16x16x32_bf16(
                        af[mi].s, bf[ni].s, acc[mi][ni], 0, 0, 0);
        }
        __syncthreads();
    }

    const int m0 = mt64 * 64;
    const int n0 = nt64 * 64;
#pragma unroll
    for (int mi = 0; mi < 2; ++mi) {
#pragma unroll
        for (int ni = 0; ni < 2; ++ni) {
            int col = n0 + wn + ni * 16 + l15;
            float bv = bias[col];
#pragma unroll
            for (int r = 0; r < 4; ++r) {
                int row = m0 + wm + mi * 16 + quad * 4 + r;
                Cout[(size_t)row * DD + col] = acc[mi][ni][r] + bv;
            }
        }
    }
}

// ---------------------------------------------------------------------------
// blend_kv: K' AND V' blended; written in per-128-s-quarter swizzled chunk
// layouts so attn stages them with pure global_load_lds.
// K2g[(bh*4+qd)*1024 + sl*8 + (cc^(sl&7))]  (chunk = 8 bf16 of row sl)
// Vtg[(bh*4+qd)*1024 + d*16 + (scl&8) + ((scl^d)&7)]  (chunk = 8 s at dim d)
// grid 256 = bh x 4 quarters, 256 thr.
// ---------------------------------------------------------------------------
__global__ __launch_bounds__(256) void blend_kv_kernel(
    const unsigned short* __restrict__ kb, const unsigned short* __restrict__ vb,
    unsigned short* __restrict__ K2g, unsigned short* __restrict__ Vtg)
{
    __shared__ float vt[130][65];
    const int bh = blockIdx.x >> 2;
    const int qd = blockIdx.x & 3;
    const int s0 = qd * 128;
    const int tid = threadIdx.x;
    const unsigned short* kbase = kb + (size_t)bh * SS * HDIM;
    const unsigned short* vbase = vb + (size_t)bh * SS * HDIM;
    unsigned short* Kq = K2g + ((size_t)(bh * 4 + qd)) * 8192;
    unsigned short* Vq = Vtg + ((size_t)(bh * 4 + qd)) * 8192;

    // ---- stage raw V rows s0-1 .. s0+128 into LDS (for transpose)
    for (int i = tid; i < 130 * 8; i += 256) {
        int row = i >> 3, c8 = (i & 7) << 3;
        int s = s0 + row - 1; s = s < 0 ? 0 : (s > SS - 1 ? SS - 1 : s);
        F8 vv = *(const F8*)(vbase + (size_t)s * 64 + c8);
#pragma unroll
        for (int j = 0; j < 8; ++j) vt[row][c8 + j] = bfu(vv.h[j]);
    }

    // ---- K': blend from global, write swizzled row-chunks
    for (int i = tid; i < 1024; i += 256) {
        int sl = i >> 3, cc = i & 7;
        int s = s0 + sl;
        int sm = s ? s - 1 : 0;
        int sp = (s < SS - 1) ? s + 1 : SS - 1;
        F8 k0 = *(const F8*)(kbase + (size_t)s  * 64 + cc * 8);
        F8 km = *(const F8*)(kbase + (size_t)sm * 64 + cc * 8);
        F8 kp = *(const F8*)(kbase + (size_t)sp * 64 + cc * 8);
        F8 o;
#pragma unroll
        for (int j = 0; j < 8; ++j)
            o.h[j] = f2bf(0.75f * bfu(k0.h[j]) + 0.125f * (bfu(km.h[j]) + bfu(kp.h[j])));
        *(uint4*)(Kq + (size_t)(sl * 8 + (cc ^ (sl & 7))) * 8) = *(uint4*)&o;
    }
    __syncthreads();

    // ---- V': blend + transpose from LDS, write swizzled [d][s-chunk]
    for (int i = tid; i < 1024; i += 256) {
        int d = i >> 4, scl = i & 15;
        F8 o;
#pragma unroll
        for (int a = 0; a < 8; ++a) {
            int rl = scl * 8 + a;        // local row; vt row = rl+1 is center
            o.h[a] = f2bf(0.75f * vt[rl + 1][d] + 0.125f * (vt[rl][d] + vt[rl + 2][d]));
        }
        int chunk = d * 16 + (scl & 8) + ((scl ^ d) & 7);
        *(uint4*)(Vq + (size_t)chunk * 8) = *(uint4*)&o;
    }
}

// ---------------------------------------------------------------------------
// Dense masked flash attention, quarter-pipelined: double-buffered
// global_load_lds staging (16KB K + 16KB V per 128-s quarter), no-max
// softmax with fused mask*exp, swizzled-chunk output for gemm2.
// LDS = 2*32KB + 16KB = 80KB.
// ---------------------------------------------------------------------------
__global__ __launch_bounds__(512) void attn_kernel(
    const unsigned short* __restrict__ qb,
    const unsigned short* __restrict__ K2g,   // quarter-swizzled K'
    const unsigned short* __restrict__ Vtg,   // quarter-swizzled V'^T
    const unsigned int* __restrict__ maskg,
    unsigned short* __restrict__ attn_sw)
{
    __shared__ __align__(16) unsigned short Ks2[2][8192];
    __shared__ __align__(16) unsigned short Vs2[2][8192];
    __shared__ __align__(16) unsigned short Ps[8192];

    const int bh = blockIdx.x >> 2;
    const int qt = blockIdx.x & 3;
    const int b = bh >> 4, h = bh & 15;
    const int tid  = threadIdx.x;
    const int lane = tid & 63;
    const int wid  = tid >> 6;
    const int l15  = lane & 15;
    const int quad = lane >> 4;

    const unsigned short* Kbh = K2g + (size_t)bh * 4 * 8192;
    const unsigned short* Vbh = Vtg + (size_t)bh * 4 * 8192;

    // stage quarter qd into buffer bufi (pure DMA; 4 instrs/wave)
    #define STAGE(qd, bufi) do {                                              \
        const unsigned short* kq = Kbh + (size_t)(qd) * 8192;                 \
        const unsigned short* vq = Vbh + (size_t)(qd) * 8192;                 \
        GLOAD_LDS16(kq + wid * 1024 + lane * 8,       Ks2[bufi] + wid * 1024 + lane * 8);        \
        GLOAD_LDS16(kq + wid * 1024 + 512 + lane * 8, Ks2[bufi] + wid * 1024 + 512 + lane * 8);  \
        GLOAD_LDS16(vq + wid * 1024 + lane * 8,       Vs2[bufi] + wid * 1024 + lane * 8);        \
        GLOAD_LDS16(vq + wid * 1024 + 512 + lane * 8, Vs2[bufi] + wid * 1024 + 512 + lane * 8);  \
    } while (0)

    const int qbase = qt * 128 + wid * 16;
    const int q = qbase + l15;

    F8 qf[2];
    {
        const unsigned short* qrow = qb + ((size_t)bh * SS + q) * 64;
        qf[0] = *(const F8*)(qrow + quad * 8);
        qf[1] = *(const F8*)(qrow + 32 + quad * 8);
    }

    STAGE(0, 0);
    __syncthreads();

    floatx4 accO[4];
#pragma unroll
    for (int dt = 0; dt < 4; ++dt) accO[dt] = (floatx4){0.f, 0.f, 0.f, 0.f};
    float lsum = 0.f;
    unsigned int* Pw = (unsigned int*)Ps + wid * 512;

    for (int qd = 0; qd < 4; ++qd) {
        if (qd < 3) STAGE(qd + 1, (qd + 1) & 1);
        const unsigned short* Ksb = Ks2[qd & 1];
        const unsigned short* Vsb = Vs2[qd & 1];

        // ---- S^T: 8 s-tiles of 16 (quarter-local)
        floatx4 accS[8];
#pragma unroll
        for (int st = 0; st < 8; ++st) {
            int srow = st * 16 + l15;
            const F8 k0 = *(const F8*)(Ksb + (((srow << 3) | ( quad      ^ (srow & 7))) << 3));
            const F8 k1 = *(const F8*)(Ksb + (((srow << 3) | ((4 + quad) ^ (srow & 7))) << 3));
            floatx4 a = (floatx4){0.f, 0.f, 0.f, 0.f};
            a = __builtin_amdgcn_mfma_f32_16x16x32_bf16(k0.s, qf[0].s, a, 0, 0, 0);
            a = __builtin_amdgcn_mfma_f32_16x16x32_bf16(k1.s, qf[1].s, a, 0, 0, 0);
            accS[st] = a;
        }

        // ---- PV: 2 chunks of 64 s; mask*exp fused
#pragma unroll
        for (int ch2 = 0; ch2 < 2; ++ch2) {
            unsigned int mw0 = maskg[(qd * 4 + ch2 * 2) * SS + q];
            unsigned int mw1 = maskg[(qd * 4 + ch2 * 2 + 1) * SS + q];
#pragma unroll
            for (int t = 0; t < 4; ++t) {
                unsigned int mw = (t & 2) ? mw1 : mw0;
                int sbase = (t & 1) * 16 + quad * 4;
                floatx4 a = accS[ch2 * 4 + t];
                float e0 = ((mw >> (sbase + 0)) & 1u) ? __expf(a[0] * SCALE_F) : 0.f;
                float e1 = ((mw >> (sbase + 1)) & 1u) ? __expf(a[1] * SCALE_F) : 0.f;
                float e2 = ((mw >> (sbase + 2)) & 1u) ? __expf(a[2] * SCALE_F) : 0.f;
                float e3 = ((mw >> (sbase + 3)) & 1u) ? __expf(a[3] * SCALE_F) : 0.f;
                lsum += (e0 + e1) + (e2 + e3);
                unsigned int w0 = (unsigned int)f2bf(e0) | ((unsigned int)f2bf(e1) << 16);
                unsigned int w1 = (unsigned int)f2bf(e2) | ((unsigned int)f2bf(e3) << 16);
                int off0 = t * 8 + quad * 2;
                int off1 = off0 + 1;
                Pw[l15 * 32 + ((((off0 >> 2) ^ (l15 & 7)) << 2) | (off0 & 3))] = w0;
                Pw[l15 * 32 + ((((off1 >> 2) ^ (l15 & 7)) << 2) | (off1 & 3))] = w1;
            }
            F8 pa[2];
#pragma unroll
            for (int ks = 0; ks < 2; ++ks) {
                int ci = ks * 4 + quad;
                pa[ks] = *(const F8*)((const unsigned short*)(Pw + l15 * 32) +
                                      ((ci ^ (l15 & 7)) << 3));
            }
#pragma unroll
            for (int dt = 0; dt < 4; ++dt) {
                int d = dt * 16 + l15;
#pragma unroll
                for (int ks = 0; ks < 2; ++ks) {
                    int scl = ch2 * 8 + ks * 4 + quad;
                    int chunk = d * 16 + (scl & 8) + ((scl ^ d) & 7);
                    const F8 bv = *(const F8*)(Vsb + ((size_t)chunk << 3));
                    accO[dt] = __builtin_amdgcn_mfma_f32_16x16x32_bf16(pa[ks].s, bv.s, accO[dt], 0, 0, 0);
                }
            }
        }
        __syncthreads();   // qd+1 loads landed; buf (qd&1) free for qd+2
    }

    lsum += __shfl_xor(lsum, 16);
    lsum += __shfl_xor(lsum, 32);
    float inv = 1.0f / lsum;

    unsigned short* Ow = Ps + wid * 1024;
#pragma unroll
    for (int r = 0; r < 4; ++r) {
        float invr = __shfl(inv, quad * 4 + r);
#pragma unroll
        for (int dt = 0; dt < 4; ++dt)
            Ow[(quad * 4 + r) * 64 + dt * 16 + l15] = f2bf(accO[dt][r] * invr);
    }
#pragma unroll
    for (int i = 0; i < 2; ++i) {
        int ch = i * 64 + lane;
        int qlocal = ch >> 3, j = ch & 7;
        int qq = qt * 128 + wid * 16 + qlocal;
        int mrow = b * SS + qq;
        int mt = mrow >> 7, rr = mrow & 127;
        int kt2 = h * 2 + (j >> 2), c = j & 3;
        size_t gid = (((size_t)(mt * 32 + kt2) * 4 + c) * 128 + rr);
        *(uint4*)(attn_sw + gid * 8) = *(const uint4*)(Ow + qlocal * 64 + j * 8);
    }
    #undef STAGE
}

// ---------------------------------------------------------------------------
extern "C" void kernel_launch(void* const* d_in, const int* in_sizes, int n_in,
                              void* d_out, int out_size, void* d_ws, size_t ws_size,
                              hipStream_t stream)
{
    const float* x     = (const float*)d_in[0];
    const float* w_qkv = (const float*)d_in[1];
    const float* b_qkv = (const float*)d_in[2];
    const float* w_out = (const float*)d_in[3];
    const float* b_out = (const float*)d_in[4];
    const int* routes  = (const int*)d_in[5];

    char* w = (char*)d_ws;
    unsigned short* xb_sw  = (unsigned short*)(w);                 // 4 MB
    unsigned short* wb1_sw = (unsigned short*)(w + (4u  << 20));   // 6 MB
    unsigned short* wb2_sw = (unsigned short*)(w + (10u << 20));   // 2 MB
    unsigned short* qbuf   = (unsigned short*)(w + (12u << 20));   // 4 MB
    unsigned short* kbuf   = (unsigned short*)(w + (16u << 20));   // 4 MB
    unsigned short* vbuf   = (unsigned short*)(w + (20u << 20));   // 4 MB
    unsigned short* K2g    = (unsigned short*)(w + (24u << 20));   // 4 MB
    unsigned short* Vtg    = (unsigned short*)(w + (28u << 20));   // 4 MB
    unsigned short* attnsw = (unsigned short*)(w + (32u << 20));   // 4 MB
    unsigned int*   maskg  = (unsigned int*)(w + (36u << 20));     // 32 KB

    prep_kernel<<<3074, 256, 0, stream>>>(x, w_qkv, w_out, routes,
                                          xb_sw, wb1_sw, wb2_sw, maskg);

    gemm_qkv<<<768, 256, 0, stream>>>(xb_sw, wb1_sw, b_qkv, qbuf, kbuf, vbuf);

    blend_kv_kernel<<<256, 256, 0, stream>>>(kbuf, vbuf, K2g, Vtg);

    attn_kernel<<<256, 512, 0, stream>>>(qbuf, K2g, Vtg, maskg, attnsw);

    gemm_out<<<512, 256, 0, stream>>>(attnsw, wb2_sw, b_out, (float*)d_out);
}

// Round 13
// 144.544 us; speedup vs baseline: 1.1213x; 1.0062x over previous
//
#include <hip/hip_runtime.h>
#include <hip/hip_bf16.h>

#define BB 4
#define SS 512
#define DD 1024
#define HH 16
#define KR 64
#define HDIM 64
#define THREE_D 3072
#define M_ROWS 2048
#define SCALE_F 0.125f

typedef __attribute__((ext_vector_type(8))) short short8;
typedef __attribute__((ext_vector_type(4))) float floatx4;

union F8 { short8 s; unsigned int u[4]; unsigned short h[8]; };

__device__ inline float bfu(unsigned short h){ union{unsigned int u; float f;} c; c.u = ((unsigned int)h) << 16; return c.f; }
__device__ inline unsigned short f2bf(float f){
    union{float f; unsigned int u;} c; c.f = f;
    unsigned int u = c.u;
    return (unsigned short)((u + 0x7fffu + ((u >> 16) & 1u)) >> 16);   // RNE
}

#define GLOAD_LDS16(g, l)                                                     \
    __builtin_amdgcn_global_load_lds(                                         \
        (const __attribute__((address_space(1))) unsigned int*)(g),           \
        (__attribute__((address_space(3))) unsigned int*)(l), 16, 0, 0)

// ---------------------------------------------------------------------------
// prep: fused cvtA (x->swizzled bf16) + cvtB(w_qkv) + cvtB(w_out) + mask
// ---------------------------------------------------------------------------
__global__ __launch_bounds__(256) void prep_kernel(
    const float* __restrict__ x, const float* __restrict__ w_qkv,
    const float* __restrict__ w_out, const int* __restrict__ routes,
    unsigned short* __restrict__ xb_sw, unsigned short* __restrict__ wb1_sw,
    unsigned short* __restrict__ wb2_sw, unsigned int* __restrict__ maskg)
{
    const int bx = blockIdx.x;
    const int tid = threadIdx.x;
    if (bx < 1024) {
        int gid = bx * 256 + tid;
        int r  = gid & 127;
        int c  = (gid >> 7) & 3;
        int kt = (gid >> 9) & 31;
        int mt = gid >> 14;
        const float* src = x + ((size_t)(mt * 128 + r)) * 1024 + kt * 32 + c * 8;
        float4 a = *(const float4*)src;
        float4 b = *(const float4*)(src + 4);
        F8 o;
        o.h[0] = f2bf(a.x); o.h[1] = f2bf(a.y); o.h[2] = f2bf(a.z); o.h[3] = f2bf(a.w);
        o.h[4] = f2bf(b.x); o.h[5] = f2bf(b.y); o.h[6] = f2bf(b.z); o.h[7] = f2bf(b.w);
        *(uint4*)(xb_sw + (size_t)gid * 8) = *(uint4*)&o;
    } else if (bx < 3072) {
        const float* w;
        unsigned short* out;
        int gid, N;
        if (bx < 2560) { w = w_qkv; out = wb1_sw; N = THREE_D; gid = (bx - 1024) * 256 + tid; }
        else           { w = w_out; out = wb2_sw; N = DD;      gid = (bx - 2560) * 256 + tid; }
        int r  = gid & 127;
        int c  = (gid >> 7) & 3;
        int kt = (gid >> 9) & 31;
        int nt = gid >> 14;
        int n = nt * 128 + r;
        int kbase = kt * 32 + c * 8;
        F8 o;
#pragma unroll
        for (int j = 0; j < 8; ++j)
            o.h[j] = f2bf(w[(size_t)(kbase + j) * N + n]);
        *(uint4*)(out + (size_t)gid * 8) = *(uint4*)&o;
    } else {
        int q = (bx - 3072) * 256 + tid;
        unsigned int w[16];
#pragma unroll
        for (int i = 0; i < 16; ++i) w[i] = 0u;
        for (int j = 0; j < KR; ++j) {
            int r = routes[q * KR + j];
            if (r <= q) w[r >> 5] |= 1u << (r & 31);
        }
#pragma unroll
        for (int sw = 0; sw < 16; ++sw) maskg[sw * SS + q] = w[sw];
    }
}

// ---------------------------------------------------------------------------
// GEMM1 (QKV): 64x128 tile, BK=128 (8 iters, 16 barriers) -> 768 blocks=3/CU.
// LDS 48KB staging (unioned with epilogue tile).
// ---------------------------------------------------------------------------
__global__ __launch_bounds__(256) void gemm_qkv(
    const unsigned short* __restrict__ Asw,
    const unsigned short* __restrict__ Bsw,
    const float* __restrict__ bias,
    unsigned short* __restrict__ qb, unsigned short* __restrict__ kb,
    unsigned short* __restrict__ vb)
{
    __shared__ __align__(16) unsigned short Sh[24576];   // 48 KB
    unsigned short* Alds = Sh;            // 4 kh x 2048
    unsigned short* Blds = Sh + 8192;     // 4 kh x 4096

    const int tid  = threadIdx.x;
    const int lane = tid & 63;
    const int wid  = tid >> 6;
    const int l15  = lane & 15;
    const int quad = lane >> 4;

    const int bid  = blockIdx.x;
    const int xcd  = bid & 7;
    const int loc  = bid >> 3;
    const int mt64 = (xcd & 3) * 8 + (loc & 7);
    const int nt   = (xcd >> 2) * 12 + (loc >> 3);

    const int mt = mt64 >> 1;
    const int rh = (mt64 & 1) * 64;
    const int wn = wid * 32;

    floatx4 acc[4][2];
#pragma unroll
    for (int i = 0; i < 4; ++i)
#pragma unroll
        for (int j = 0; j < 2; ++j) acc[i][j] = (floatx4){0.f, 0.f, 0.f, 0.f};

    for (int kt8 = 0; kt8 < 8; ++kt8) {
#pragma unroll
        for (int kh = 0; kh < 4; ++kh) {
            int kt = kt8 * 4 + kh;
            const unsigned short* ga = Asw + ((size_t)(mt * 32 + kt) * 4 + wid) * 1024 + (rh + lane) * 8;
            const unsigned short* gb = Bsw + (size_t)(nt * 32 + kt) * 4096 + wid * 1024 + lane * 8;
            GLOAD_LDS16(ga,       Alds + kh * 2048 + wid * 512 + lane * 8);
            GLOAD_LDS16(gb,       Blds + kh * 4096 + wid * 1024 + lane * 8);
            GLOAD_LDS16(gb + 512, Blds + kh * 4096 + wid * 1024 + 512 + lane * 8);
        }
        __syncthreads();

#pragma unroll
        for (int kh = 0; kh < 4; ++kh) {
            F8 af[4], bf[2];
#pragma unroll
            for (int mi = 0; mi < 4; ++mi)
                af[mi] = *(const F8*)(Alds + kh * 2048 + (size_t)(quad * 64 + mi * 16 + l15) * 8);
#pragma unroll
            for (int ni = 0; ni < 2; ++ni)
                bf[ni] = *(const F8*)(Blds + kh * 4096 + (size_t)(quad * 128 + wn + ni * 16 + l15) * 8);
#pragma unroll
            for (int mi = 0; mi < 4; ++mi)
#pragma unroll
                for (int ni = 0; ni < 2; ++ni)
                    acc[mi][ni] = __builtin_amdgcn_mfma_f32_16x16x32_bf16(
                        af[mi].s, bf[ni].s, acc[mi][ni], 0, 0, 0);
        }
        __syncthreads();
    }

    const int m0 = mt64 * 64;
    const int n0 = nt * 128;

#pragma unroll
    for (int mi = 0; mi < 4; ++mi) {
#pragma unroll
        for (int ni = 0; ni < 2; ++ni) {
            int col = wn + ni * 16 + l15;
            float bv = bias[n0 + col];
#pragma unroll
            for (int r = 0; r < 4; ++r) {
                int row = mi * 16 + quad * 4 + r;
                Sh[row * 136 + col] = f2bf(acc[mi][ni][r] + bv);
            }
        }
    }
    __syncthreads();

    for (int i = tid; i < 1024; i += 256) {
        int rr = i >> 4, cc = i & 15;
        int grow = m0 + rr, gcol = n0 + cc * 8;
        int b = grow >> 9, s = grow & 511;
        int which = gcol >> 10, rem = gcol & 1023;
        int h = rem >> 6, hd = rem & 63;
        unsigned short* dst = (which == 0) ? qb : (which == 1) ? kb : vb;
        uint4 val = *(const uint4*)(Sh + rr * 136 + cc * 8);
        *(uint4*)(dst + (((size_t)(b * HH + h) * SS) + s) * HDIM + hd) = val;
    }
}

// ---------------------------------------------------------------------------
// GEMM2 (out proj): 64x64 tile, BK=64 -> 512 blocks = 2/CU. (unchanged)
// ---------------------------------------------------------------------------
__global__ __launch_bounds__(256) void gemm_out(
    const unsigned short* __restrict__ Asw,
    const unsigned short* __restrict__ Bsw,
    const float* __restrict__ bias,
    float* __restrict__ Cout)
{
    __shared__ __align__(16) unsigned short Alds[4096];
    __shared__ __align__(16) unsigned short Blds[4096];

    const int tid  = threadIdx.x;
    const int lane = tid & 63;
    const int wid  = tid >> 6;
    const int l15  = lane & 15;
    const int quad = lane >> 4;

    const int bid  = blockIdx.x;
    const int xcd  = bid & 7;
    const int loc  = bid >> 3;
    const int mt64 = (xcd & 3) * 8 + (loc & 7);
    const int nt64 = (xcd >> 2) * 8 + (loc >> 3);

    const int mt  = mt64 >> 1;
    const int rh  = (mt64 & 1) * 64;
    const int ntB = nt64 >> 1;
    const int rhB = (nt64 & 1) * 64;
    const int wm  = (wid >> 1) * 32;
    const int wn  = (wid & 1) * 32;

    floatx4 acc[2][2];
#pragma unroll
    for (int i = 0; i < 2; ++i)
#pragma unroll
        for (int j = 0; j < 2; ++j) acc[i][j] = (floatx4){0.f, 0.f, 0.f, 0.f};

    for (int kt2 = 0; kt2 < 16; ++kt2) {
#pragma unroll
        for (int kh = 0; kh < 2; ++kh) {
            int kt = kt2 * 2 + kh;
            const unsigned short* ga = Asw + ((size_t)(mt  * 32 + kt) * 4 + wid) * 1024 + (rh  + lane) * 8;
            const unsigned short* gb = Bsw + ((size_t)(ntB * 32 + kt) * 4 + wid) * 1024 + (rhB + lane) * 8;
            GLOAD_LDS16(ga, Alds + kh * 2048 + wid * 512 + lane * 8);
            GLOAD_LDS16(gb, Blds + kh * 2048 + wid * 512 + lane * 8);
        }
        __syncthreads();

#pragma unroll
        for (int kh = 0; kh < 2; ++kh) {
            F8 af[2], bf[2];
#pragma unroll
            for (int mi = 0; mi < 2; ++mi)
                af[mi] = *(const F8*)(Alds + kh * 2048 + (size_t)(quad * 64 + wm + mi * 16 + l15) * 8);
#pragma unroll
            for (int ni = 0; ni < 2; ++ni)
                bf[ni] = *(const F8*)(Blds + kh * 2048 + (size_t)(quad * 64 + wn + ni * 16 + l15) * 8);
#pragma unroll
            for (int mi = 0; mi < 2; ++mi)
#pragma unroll
                for (int ni = 0; ni < 2; ++ni)
                    acc[mi][ni] = __builtin_amdgcn_mfma_f32_16x16x32_bf16(
                        af[mi].s, bf[ni].s, acc[mi][ni], 0, 0, 0);
        }
        __syncthreads();
    }

    const int m0 = mt64 * 64;
    const int n0 = nt64 * 64;
#pragma unroll
    for (int mi = 0; mi < 2; ++mi) {
#pragma unroll
        for (int ni = 0; ni < 2; ++ni) {
            int col = n0 + wn + ni * 16 + l15;
            float bv = bias[col];
#pragma unroll
            for (int r = 0; r < 4; ++r) {
                int row = m0 + wm + mi * 16 + quad * 4 + r;
                Cout[(size_t)row * DD + col] = acc[mi][ni][r] + bv;
            }
        }
    }
}

// ---------------------------------------------------------------------------
// blend_kv: K'/V' blended, written in per-128-s-quarter swizzled chunk
// layouts for pure global_load_lds staging in attn. (unchanged from R12)
// ---------------------------------------------------------------------------
__global__ __launch_bounds__(256) void blend_kv_kernel(
    const unsigned short* __restrict__ kb, const unsigned short* __restrict__ vb,
    unsigned short* __restrict__ K2g, unsigned short* __restrict__ Vtg)
{
    __shared__ float vt[130][65];
    const int bh = blockIdx.x >> 2;
    const int qd = blockIdx.x & 3;
    const int s0 = qd * 128;
    const int tid = threadIdx.x;
    const unsigned short* kbase = kb + (size_t)bh * SS * HDIM;
    const unsigned short* vbase = vb + (size_t)bh * SS * HDIM;
    unsigned short* Kq = K2g + ((size_t)(bh * 4 + qd)) * 8192;
    unsigned short* Vq = Vtg + ((size_t)(bh * 4 + qd)) * 8192;

    for (int i = tid; i < 130 * 8; i += 256) {
        int row = i >> 3, c8 = (i & 7) << 3;
        int s = s0 + row - 1; s = s < 0 ? 0 : (s > SS - 1 ? SS - 1 : s);
        F8 vv = *(const F8*)(vbase + (size_t)s * 64 + c8);
#pragma unroll
        for (int j = 0; j < 8; ++j) vt[row][c8 + j] = bfu(vv.h[j]);
    }

    for (int i = tid; i < 1024; i += 256) {
        int sl = i >> 3, cc = i & 7;
        int s = s0 + sl;
        int sm = s ? s - 1 : 0;
        int sp = (s < SS - 1) ? s + 1 : SS - 1;
        F8 k0 = *(const F8*)(kbase + (size_t)s  * 64 + cc * 8);
        F8 km = *(const F8*)(kbase + (size_t)sm * 64 + cc * 8);
        F8 kp = *(const F8*)(kbase + (size_t)sp * 64 + cc * 8);
        F8 o;
#pragma unroll
        for (int j = 0; j < 8; ++j)
            o.h[j] = f2bf(0.75f * bfu(k0.h[j]) + 0.125f * (bfu(km.h[j]) + bfu(kp.h[j])));
        *(uint4*)(Kq + (size_t)(sl * 8 + (cc ^ (sl & 7))) * 8) = *(uint4*)&o;
    }
    __syncthreads();

    for (int i = tid; i < 1024; i += 256) {
        int d = i >> 4, scl = i & 15;
        F8 o;
#pragma unroll
        for (int a = 0; a < 8; ++a) {
            int rl = scl * 8 + a;
            o.h[a] = f2bf(0.75f * vt[rl + 1][d] + 0.125f * (vt[rl][d] + vt[rl + 2][d]));
        }
        int chunk = d * 16 + (scl & 8) + ((scl ^ d) & 7);
        *(uint4*)(Vq + (size_t)chunk * 8) = *(uint4*)&o;
    }
}

// ---------------------------------------------------------------------------
// Dense masked flash attention, quarter-pipelined DMA staging.
// 256 thr (4 waves x 16 q = 64-q tile) -> 512 blocks, LDS 72KB = 2 blocks/CU.
// XCD swizzle: each XCD owns 8 bh x 8 qt (one K/V fetch per bh per XCD).
// ---------------------------------------------------------------------------
__global__ __launch_bounds__(256) void attn_kernel(
    const unsigned short* __restrict__ qb,
    const unsigned short* __restrict__ K2g,
    const unsigned short* __restrict__ Vtg,
    const unsigned int* __restrict__ maskg,
    unsigned short* __restrict__ attn_sw)
{
    __shared__ __align__(16) unsigned short Ks2[2][8192];  // 32 KB
    __shared__ __align__(16) unsigned short Vs2[2][8192];  // 32 KB
    __shared__ __align__(16) unsigned short Ps[4096];      // 8 KB

    const int bid = blockIdx.x;
    const int xcd = bid & 7;
    const int loc = bid >> 3;                 // 0..63
    const int bh  = xcd * 8 + (loc & 7);      // 0..63
    const int qt  = loc >> 3;                 // 0..7
    const int b = bh >> 4, h = bh & 15;
    const int tid  = threadIdx.x;
    const int lane = tid & 63;
    const int wid  = tid >> 6;                // 0..3
    const int l15  = lane & 15;
    const int quad = lane >> 4;

    const unsigned short* Kbh = K2g + (size_t)bh * 4 * 8192;
    const unsigned short* Vbh = Vtg + (size_t)bh * 4 * 8192;

    // stage quarter qd into buffer bufi (pure DMA; 8 instrs/wave)
    #define STAGE(qd, bufi) do {                                              \
        const unsigned short* kq = Kbh + (size_t)(qd) * 8192 + wid * 2048;    \
        const unsigned short* vq = Vbh + (size_t)(qd) * 8192 + wid * 2048;    \
        unsigned short* kl = Ks2[bufi] + wid * 2048;                          \
        unsigned short* vl = Vs2[bufi] + wid * 2048;                          \
        GLOAD_LDS16(kq + lane * 8,        kl + lane * 8);                     \
        GLOAD_LDS16(kq + 512 + lane * 8,  kl + 512 + lane * 8);               \
        GLOAD_LDS16(kq + 1024 + lane * 8, kl + 1024 + lane * 8);              \
        GLOAD_LDS16(kq + 1536 + lane * 8, kl + 1536 + lane * 8);              \
        GLOAD_LDS16(vq + lane * 8,        vl + lane * 8);                     \
        GLOAD_LDS16(vq + 512 + lane * 8,  vl + 512 + lane * 8);               \
        GLOAD_LDS16(vq + 1024 + lane * 8, vl + 1024 + lane * 8);              \
        GLOAD_LDS16(vq + 1536 + lane * 8, vl + 1536 + lane * 8);              \
    } while (0)

    const int q = qt * 64 + wid * 16 + l15;

    F8 qf[2];
    {
        const unsigned short* qrow = qb + ((size_t)bh * SS + q) * 64;
        qf[0] = *(const F8*)(qrow + quad * 8);
        qf[1] = *(const F8*)(qrow + 32 + quad * 8);
    }

    STAGE(0, 0);
    __syncthreads();

    floatx4 accO[4];
#pragma unroll
    for (int dt = 0; dt < 4; ++dt) accO[dt] = (floatx4){0.f, 0.f, 0.f, 0.f};
    float lsum = 0.f;
    unsigned int* Pw = (unsigned int*)Ps + wid * 512;

    for (int qd = 0; qd < 4; ++qd) {
        if (qd < 3) STAGE(qd + 1, (qd + 1) & 1);
        const unsigned short* Ksb = Ks2[qd & 1];
        const unsigned short* Vsb = Vs2[qd & 1];

        // ---- S^T: 8 s-tiles of 16 (quarter-local)
        floatx4 accS[8];
#pragma unroll
        for (int st = 0; st < 8; ++st) {
            int srow = st * 16 + l15;
            const F8 k0 = *(const F8*)(Ksb + (((srow << 3) | ( quad      ^ (srow & 7))) << 3));
            const F8 k1 = *(const F8*)(Ksb + (((srow << 3) | ((4 + quad) ^ (srow & 7))) << 3));
            floatx4 a = (floatx4){0.f, 0.f, 0.f, 0.f};
            a = __builtin_amdgcn_mfma_f32_16x16x32_bf16(k0.s, qf[0].s, a, 0, 0, 0);
            a = __builtin_amdgcn_mfma_f32_16x16x32_bf16(k1.s, qf[1].s, a, 0, 0, 0);
            accS[st] = a;
        }

        // ---- PV: 2 chunks of 64 s; mask*exp fused
#pragma unroll
        for (int ch2 = 0; ch2 < 2; ++ch2) {
            unsigned int mw0 = maskg[(qd * 4 + ch2 * 2) * SS + q];
            unsigned int mw1 = maskg[(qd * 4 + ch2 * 2 + 1) * SS + q];
#pragma unroll
            for (int t = 0; t < 4; ++t) {
                unsigned int mw = (t & 2) ? mw1 : mw0;
                int sbase = (t & 1) * 16 + quad * 4;
                floatx4 a = accS[ch2 * 4 + t];
                float e0 = ((mw >> (sbase + 0)) & 1u) ? __expf(a[0] * SCALE_F) : 0.f;
                float e1 = ((mw >> (sbase + 1)) & 1u) ? __expf(a[1] * SCALE_F) : 0.f;
                float e2 = ((mw >> (sbase + 2)) & 1u) ? __expf(a[2] * SCALE_F) : 0.f;
                float e3 = ((mw >> (sbase + 3)) & 1u) ? __expf(a[3] * SCALE_F) : 0.f;
                lsum += (e0 + e1) + (e2 + e3);
                unsigned int w0 = (unsigned int)f2bf(e0) | ((unsigned int)f2bf(e1) << 16);
                unsigned int w1 = (unsigned int)f2bf(e2) | ((unsigned int)f2bf(e3) << 16);
                int off0 = t * 8 + quad * 2;
                int off1 = off0 + 1;
                Pw[l15 * 32 + ((((off0 >> 2) ^ (l15 & 7)) << 2) | (off0 & 3))] = w0;
                Pw[l15 * 32 + ((((off1 >> 2) ^ (l15 & 7)) << 2) | (off1 & 3))] = w1;
            }
            F8 pa[2];
#pragma unroll
            for (int ks = 0; ks < 2; ++ks) {
                int ci = ks * 4 + quad;
                pa[ks] = *(const F8*)((const unsigned short*)(Pw + l15 * 32) +
                                      ((ci ^ (l15 & 7)) << 3));
            }
#pragma unroll
            for (int dt = 0; dt < 4; ++dt) {
                int d = dt * 16 + l15;
#pragma unroll
                for (int ks = 0; ks < 2; ++ks) {
                    int scl = ch2 * 8 + ks * 4 + quad;
                    int chunk = d * 16 + (scl & 8) + ((scl ^ d) & 7);
                    const F8 bv = *(const F8*)(Vsb + ((size_t)chunk << 3));
                    accO[dt] = __builtin_amdgcn_mfma_f32_16x16x32_bf16(pa[ks].s, bv.s, accO[dt], 0, 0, 0);
                }
            }
        }
        __syncthreads();   // qd+1 loads landed; buf (qd&1) free for qd+2
    }

    lsum += __shfl_xor(lsum, 16);
    lsum += __shfl_xor(lsum, 32);
    float inv = 1.0f / lsum;

    unsigned short* Ow = Ps + wid * 1024;
#pragma unroll
    for (int r = 0; r < 4; ++r) {
        float invr = __shfl(inv, quad * 4 + r);
#pragma unroll
        for (int dt = 0; dt < 4; ++dt)
            Ow[(quad * 4 + r) * 64 + dt * 16 + l15] = f2bf(accO[dt][r] * invr);
    }
#pragma unroll
    for (int i = 0; i < 2; ++i) {
        int ch = i * 64 + lane;
        int qlocal = ch >> 3, j = ch & 7;
        int qq = qt * 64 + wid * 16 + qlocal;
        int mrow = b * SS + qq;
        int mt = mrow >> 7, rr = mrow & 127;
        int kt2 = h * 2 + (j >> 2), c = j & 3;
        size_t gid = (((size_t)(mt * 32 + kt2) * 4 + c) * 128 + rr);
        *(uint4*)(attn_sw + gid * 8) = *(const uint4*)(Ow + qlocal * 64 + j * 8);
    }
    #undef STAGE
}

// ---------------------------------------------------------------------------
extern "C" void kernel_launch(void* const* d_in, const int* in_sizes, int n_in,
                              void* d_out, int out_size, void* d_ws, size_t ws_size,
                              hipStream_t stream)
{
    const float* x     = (const float*)d_in[0];
    const float* w_qkv = (const float*)d_in[1];
    const float* b_qkv = (const float*)d_in[2];
    const float* w_out = (const float*)d_in[3];
    const float* b_out = (const float*)d_in[4];
    const int* routes  = (const int*)d_in[5];

    char* w = (char*)d_ws;
    unsigned short* xb_sw  = (unsigned short*)(w);                 // 4 MB
    unsigned short* wb1_sw = (unsigned short*)(w + (4u  << 20));   // 6 MB
    unsigned short* wb2_sw = (unsigned short*)(w + (10u << 20));   // 2 MB
    unsigned short* qbuf   = (unsigned short*)(w + (12u << 20));   // 4 MB
    unsigned short* kbuf   = (unsigned short*)(w + (16u << 20));   // 4 MB
    unsigned short* vbuf   = (unsigned short*)(w + (20u << 20));   // 4 MB
    unsigned short* K2g    = (unsigned short*)(w + (24u << 20));   // 4 MB
    unsigned short* Vtg    = (unsigned short*)(w + (28u << 20));   // 4 MB
    unsigned short* attnsw = (unsigned short*)(w + (32u << 20));   // 4 MB
    unsigned int*   maskg  = (unsigned int*)(w + (36u << 20));     // 32 KB

    prep_kernel<<<3074, 256, 0, stream>>>(x, w_qkv, w_out, routes,
                                          xb_sw, wb1_sw, wb2_sw, maskg);

    gemm_qkv<<<768, 256, 0, stream>>>(xb_sw, wb1_sw, b_qkv, qbuf, kbuf, vbuf);

    blend_kv_kernel<<<256, 256, 0, stream>>>(kbuf, vbuf, K2g, Vtg);

    attn_kernel<<<512, 256, 0, stream>>>(qbuf, K2g, Vtg, maskg, attnsw);

    gemm_out<<<512, 256, 0, stream>>>(attnsw, wb2_sw, b_out, (float*)d_out);
}

// Round 14
// 144.507 us; speedup vs baseline: 1.1216x; 1.0003x over previous
//
#include <hip/hip_runtime.h>
#include <hip/hip_bf16.h>

#define BB 4
#define SS 512
#define DD 1024
#define HH 16
#define KR 64
#define HDIM 64
#define THREE_D 3072
#define M_ROWS 2048
#define SCALE_F 0.125f

typedef __attribute__((ext_vector_type(8))) short short8;
typedef __attribute__((ext_vector_type(4))) float floatx4;

union F8 { short8 s; unsigned int u[4]; unsigned short h[8]; };

__device__ inline float bfu(unsigned short h){ union{unsigned int u; float f;} c; c.u = ((unsigned int)h) << 16; return c.f; }
__device__ inline unsigned short f2bf(float f){
    union{float f; unsigned int u;} c; c.f = f;
    unsigned int u = c.u;
    return (unsigned short)((u + 0x7fffu + ((u >> 16) & 1u)) >> 16);   // RNE
}

#define GLOAD_LDS16(g, l)                                                     \
    __builtin_amdgcn_global_load_lds(                                         \
        (const __attribute__((address_space(1))) unsigned int*)(g),           \
        (__attribute__((address_space(3))) unsigned int*)(l), 16, 0, 0)

// ---------------------------------------------------------------------------
// prep: fused cvtA (x->swizzled bf16) + cvtB(w_qkv) + cvtB(w_out) + mask
// ---------------------------------------------------------------------------
__global__ __launch_bounds__(256) void prep_kernel(
    const float* __restrict__ x, const float* __restrict__ w_qkv,
    const float* __restrict__ w_out, const int* __restrict__ routes,
    unsigned short* __restrict__ xb_sw, unsigned short* __restrict__ wb1_sw,
    unsigned short* __restrict__ wb2_sw, unsigned int* __restrict__ maskg)
{
    const int bx = blockIdx.x;
    const int tid = threadIdx.x;
    if (bx < 1024) {
        int gid = bx * 256 + tid;
        int r  = gid & 127;
        int c  = (gid >> 7) & 3;
        int kt = (gid >> 9) & 31;
        int mt = gid >> 14;
        const float* src = x + ((size_t)(mt * 128 + r)) * 1024 + kt * 32 + c * 8;
        float4 a = *(const float4*)src;
        float4 b = *(const float4*)(src + 4);
        F8 o;
        o.h[0] = f2bf(a.x); o.h[1] = f2bf(a.y); o.h[2] = f2bf(a.z); o.h[3] = f2bf(a.w);
        o.h[4] = f2bf(b.x); o.h[5] = f2bf(b.y); o.h[6] = f2bf(b.z); o.h[7] = f2bf(b.w);
        *(uint4*)(xb_sw + (size_t)gid * 8) = *(uint4*)&o;
    } else if (bx < 3072) {
        const float* w;
        unsigned short* out;
        int gid, N;
        if (bx < 2560) { w = w_qkv; out = wb1_sw; N = THREE_D; gid = (bx - 1024) * 256 + tid; }
        else           { w = w_out; out = wb2_sw; N = DD;      gid = (bx - 2560) * 256 + tid; }
        int r  = gid & 127;
        int c  = (gid >> 7) & 3;
        int kt = (gid >> 9) & 31;
        int nt = gid >> 14;
        int n = nt * 128 + r;
        int kbase = kt * 32 + c * 8;
        F8 o;
#pragma unroll
        for (int j = 0; j < 8; ++j)
            o.h[j] = f2bf(w[(size_t)(kbase + j) * N + n]);
        *(uint4*)(out + (size_t)gid * 8) = *(uint4*)&o;
    } else {
        int q = (bx - 3072) * 256 + tid;
        unsigned int w[16];
#pragma unroll
        for (int i = 0; i < 16; ++i) w[i] = 0u;
        for (int j = 0; j < KR; ++j) {
            int r = routes[q * KR + j];
            if (r <= q) w[r >> 5] |= 1u << (r & 31);
        }
#pragma unroll
        for (int sw = 0; sw < 16; ++sw) maskg[sw * SS + q] = w[sw];
    }
}

// ---------------------------------------------------------------------------
// GEMM1 (QKV): 64x128 tile, BK=128 -> 768 blocks = 3/CU. (unchanged from R13)
// ---------------------------------------------------------------------------
__global__ __launch_bounds__(256) void gemm_qkv(
    const unsigned short* __restrict__ Asw,
    const unsigned short* __restrict__ Bsw,
    const float* __restrict__ bias,
    unsigned short* __restrict__ qb, unsigned short* __restrict__ kb,
    unsigned short* __restrict__ vb)
{
    __shared__ __align__(16) unsigned short Sh[24576];   // 48 KB
    unsigned short* Alds = Sh;
    unsigned short* Blds = Sh + 8192;

    const int tid  = threadIdx.x;
    const int lane = tid & 63;
    const int wid  = tid >> 6;
    const int l15  = lane & 15;
    const int quad = lane >> 4;

    const int bid  = blockIdx.x;
    const int xcd  = bid & 7;
    const int loc  = bid >> 3;
    const int mt64 = (xcd & 3) * 8 + (loc & 7);
    const int nt   = (xcd >> 2) * 12 + (loc >> 3);

    const int mt = mt64 >> 1;
    const int rh = (mt64 & 1) * 64;
    const int wn = wid * 32;

    floatx4 acc[4][2];
#pragma unroll
    for (int i = 0; i < 4; ++i)
#pragma unroll
        for (int j = 0; j < 2; ++j) acc[i][j] = (floatx4){0.f, 0.f, 0.f, 0.f};

    for (int kt8 = 0; kt8 < 8; ++kt8) {
#pragma unroll
        for (int kh = 0; kh < 4; ++kh) {
            int kt = kt8 * 4 + kh;
            const unsigned short* ga = Asw + ((size_t)(mt * 32 + kt) * 4 + wid) * 1024 + (rh + lane) * 8;
            const unsigned short* gb = Bsw + (size_t)(nt * 32 + kt) * 4096 + wid * 1024 + lane * 8;
            GLOAD_LDS16(ga,       Alds + kh * 2048 + wid * 512 + lane * 8);
            GLOAD_LDS16(gb,       Blds + kh * 4096 + wid * 1024 + lane * 8);
            GLOAD_LDS16(gb + 512, Blds + kh * 4096 + wid * 1024 + 512 + lane * 8);
        }
        __syncthreads();

#pragma unroll
        for (int kh = 0; kh < 4; ++kh) {
            F8 af[4], bf[2];
#pragma unroll
            for (int mi = 0; mi < 4; ++mi)
                af[mi] = *(const F8*)(Alds + kh * 2048 + (size_t)(quad * 64 + mi * 16 + l15) * 8);
#pragma unroll
            for (int ni = 0; ni < 2; ++ni)
                bf[ni] = *(const F8*)(Blds + kh * 4096 + (size_t)(quad * 128 + wn + ni * 16 + l15) * 8);
#pragma unroll
            for (int mi = 0; mi < 4; ++mi)
#pragma unroll
                for (int ni = 0; ni < 2; ++ni)
                    acc[mi][ni] = __builtin_amdgcn_mfma_f32_16x16x32_bf16(
                        af[mi].s, bf[ni].s, acc[mi][ni], 0, 0, 0);
        }
        __syncthreads();
    }

    const int m0 = mt64 * 64;
    const int n0 = nt * 128;

#pragma unroll
    for (int mi = 0; mi < 4; ++mi) {
#pragma unroll
        for (int ni = 0; ni < 2; ++ni) {
            int col = wn + ni * 16 + l15;
            float bv = bias[n0 + col];
#pragma unroll
            for (int r = 0; r < 4; ++r) {
                int row = mi * 16 + quad * 4 + r;
                Sh[row * 136 + col] = f2bf(acc[mi][ni][r] + bv);
            }
        }
    }
    __syncthreads();

    for (int i = tid; i < 1024; i += 256) {
        int rr = i >> 4, cc = i & 15;
        int grow = m0 + rr, gcol = n0 + cc * 8;
        int b = grow >> 9, s = grow & 511;
        int which = gcol >> 10, rem = gcol & 1023;
        int h = rem >> 6, hd = rem & 63;
        unsigned short* dst = (which == 0) ? qb : (which == 1) ? kb : vb;
        uint4 val = *(const uint4*)(Sh + rr * 136 + cc * 8);
        *(uint4*)(dst + (((size_t)(b * HH + h) * SS) + s) * HDIM + hd) = val;
    }
}

// ---------------------------------------------------------------------------
// GEMM2 (out proj): 64x64 tile, BK=64 -> 512 blocks = 2/CU. (unchanged)
// ---------------------------------------------------------------------------
__global__ __launch_bounds__(256) void gemm_out(
    const unsigned short* __restrict__ Asw,
    const unsigned short* __restrict__ Bsw,
    const float* __restrict__ bias,
    float* __restrict__ Cout)
{
    __shared__ __align__(16) unsigned short Alds[4096];
    __shared__ __align__(16) unsigned short Blds[4096];

    const int tid  = threadIdx.x;
    const int lane = tid & 63;
    const int wid  = tid >> 6;
    const int l15  = lane & 15;
    const int quad = lane >> 4;

    const int bid  = blockIdx.x;
    const int xcd  = bid & 7;
    const int loc  = bid >> 3;
    const int mt64 = (xcd & 3) * 8 + (loc & 7);
    const int nt64 = (xcd >> 2) * 8 + (loc >> 3);

    const int mt  = mt64 >> 1;
    const int rh  = (mt64 & 1) * 64;
    const int ntB = nt64 >> 1;
    const int rhB = (nt64 & 1) * 64;
    const int wm  = (wid >> 1) * 32;
    const int wn  = (wid & 1) * 32;

    floatx4 acc[2][2];
#pragma unroll
    for (int i = 0; i < 2; ++i)
#pragma unroll
        for (int j = 0; j < 2; ++j) acc[i][j] = (floatx4){0.f, 0.f, 0.f, 0.f};

    for (int kt2 = 0; kt2 < 16; ++kt2) {
#pragma unroll
        for (int kh = 0; kh < 2; ++kh) {
            int kt = kt2 * 2 + kh;
            const unsigned short* ga = Asw + ((size_t)(mt  * 32 + kt) * 4 + wid) * 1024 + (rh  + lane) * 8;
            const unsigned short* gb = Bsw + ((size_t)(ntB * 32 + kt) * 4 + wid) * 1024 + (rhB + lane) * 8;
            GLOAD_LDS16(ga, Alds + kh * 2048 + wid * 512 + lane * 8);
            GLOAD_LDS16(gb, Blds + kh * 2048 + wid * 512 + lane * 8);
        }
        __syncthreads();

#pragma unroll
        for (int kh = 0; kh < 2; ++kh) {
            F8 af[2], bf[2];
#pragma unroll
            for (int mi = 0; mi < 2; ++mi)
                af[mi] = *(const F8*)(Alds + kh * 2048 + (size_t)(quad * 64 + wm + mi * 16 + l15) * 8);
#pragma unroll
            for (int ni = 0; ni < 2; ++ni)
                bf[ni] = *(const F8*)(Blds + kh * 2048 + (size_t)(quad * 64 + wn + ni * 16 + l15) * 8);
#pragma unroll
            for (int mi = 0; mi < 2; ++mi)
#pragma unroll
                for (int ni = 0; ni < 2; ++ni)
                    acc[mi][ni] = __builtin_amdgcn_mfma_f32_16x16x32_bf16(
                        af[mi].s, bf[ni].s, acc[mi][ni], 0, 0, 0);
        }
        __syncthreads();
    }

    const int m0 = mt64 * 64;
    const int n0 = nt64 * 64;
#pragma unroll
    for (int mi = 0; mi < 2; ++mi) {
#pragma unroll
        for (int ni = 0; ni < 2; ++ni) {
            int col = n0 + wn + ni * 16 + l15;
            float bv = bias[col];
#pragma unroll
            for (int r = 0; r < 4; ++r) {
                int row = m0 + wm + mi * 16 + quad * 4 + r;
                Cout[(size_t)row * DD + col] = acc[mi][ni][r] + bv;
            }
        }
    }
}

// ---------------------------------------------------------------------------
// blend_kv: K'/V' blended, written in per-128-s-quarter swizzled chunk
// layouts for pure global_load_lds staging in attn. (unchanged from R12)
// ---------------------------------------------------------------------------
__global__ __launch_bounds__(256) void blend_kv_kernel(
    const unsigned short* __restrict__ kb, const unsigned short* __restrict__ vb,
    unsigned short* __restrict__ K2g, unsigned short* __restrict__ Vtg)
{
    __shared__ float vt[130][65];
    const int bh = blockIdx.x >> 2;
    const int qd = blockIdx.x & 3;
    const int s0 = qd * 128;
    const int tid = threadIdx.x;
    const unsigned short* kbase = kb + (size_t)bh * SS * HDIM;
    const unsigned short* vbase = vb + (size_t)bh * SS * HDIM;
    unsigned short* Kq = K2g + ((size_t)(bh * 4 + qd)) * 8192;
    unsigned short* Vq = Vtg + ((size_t)(bh * 4 + qd)) * 8192;

    for (int i = tid; i < 130 * 8; i += 256) {
        int row = i >> 3, c8 = (i & 7) << 3;
        int s = s0 + row - 1; s = s < 0 ? 0 : (s > SS - 1 ? SS - 1 : s);
        F8 vv = *(const F8*)(vbase + (size_t)s * 64 + c8);
#pragma unroll
        for (int j = 0; j < 8; ++j) vt[row][c8 + j] = bfu(vv.h[j]);
    }

    for (int i = tid; i < 1024; i += 256) {
        int sl = i >> 3, cc = i & 7;
        int s = s0 + sl;
        int sm = s ? s - 1 : 0;
        int sp = (s < SS - 1) ? s + 1 : SS - 1;
        F8 k0 = *(const F8*)(kbase + (size_t)s  * 64 + cc * 8);
        F8 km = *(const F8*)(kbase + (size_t)sm * 64 + cc * 8);
        F8 kp = *(const F8*)(kbase + (size_t)sp * 64 + cc * 8);
        F8 o;
#pragma unroll
        for (int j = 0; j < 8; ++j)
            o.h[j] = f2bf(0.75f * bfu(k0.h[j]) + 0.125f * (bfu(km.h[j]) + bfu(kp.h[j])));
        *(uint4*)(Kq + (size_t)(sl * 8 + (cc ^ (sl & 7))) * 8) = *(uint4*)&o;
    }
    __syncthreads();

    for (int i = tid; i < 1024; i += 256) {
        int d = i >> 4, scl = i & 15;
        F8 o;
#pragma unroll
        for (int a = 0; a < 8; ++a) {
            int rl = scl * 8 + a;
            o.h[a] = f2bf(0.75f * vt[rl + 1][d] + 0.125f * (vt[rl][d] + vt[rl + 2][d]));
        }
        int chunk = d * 16 + (scl & 8) + ((scl ^ d) & 7);
        *(uint4*)(Vq + (size_t)chunk * 8) = *(uint4*)&o;
    }
}

// ---------------------------------------------------------------------------
// Dense masked flash attention with CAUSAL CHUNK SKIPPING.
// Block stages only qt/2+1 quarters; each wave computes only s-chunks with
// chunk_start <= q_max(wave) (wave-uniform branch). Skipped chunks
// contributed exactly 0 before -> bit-identical output.
// ---------------------------------------------------------------------------
__global__ __launch_bounds__(256) void attn_kernel(
    const unsigned short* __restrict__ qb,
    const unsigned short* __restrict__ K2g,
    const unsigned short* __restrict__ Vtg,
    const unsigned int* __restrict__ maskg,
    unsigned short* __restrict__ attn_sw)
{
    __shared__ __align__(16) unsigned short Ks2[2][8192];  // 32 KB
    __shared__ __align__(16) unsigned short Vs2[2][8192];  // 32 KB
    __shared__ __align__(16) unsigned short Ps[4096];      // 8 KB

    const int bid = blockIdx.x;
    const int xcd = bid & 7;
    const int loc = bid >> 3;
    const int bh  = xcd * 8 + (loc & 7);
    const int qt  = loc >> 3;
    const int b = bh >> 4, h = bh & 15;
    const int tid  = threadIdx.x;
    const int lane = tid & 63;
    const int wid  = tid >> 6;
    const int l15  = lane & 15;
    const int quad = lane >> 4;

    const int nq    = (qt >> 1) + 1;              // quarters this block needs
    const int qmaxw = qt * 64 + wid * 16 + 15;    // wave-uniform causal bound

    const unsigned short* Kbh = K2g + (size_t)bh * 4 * 8192;
    const unsigned short* Vbh = Vtg + (size_t)bh * 4 * 8192;

    #define STAGE(qd, bufi) do {                                              \
        const unsigned short* kq = Kbh + (size_t)(qd) * 8192 + wid * 2048;    \
        const unsigned short* vq = Vbh + (size_t)(qd) * 8192 + wid * 2048;    \
        unsigned short* kl = Ks2[bufi] + wid * 2048;                          \
        unsigned short* vl = Vs2[bufi] + wid * 2048;                          \
        GLOAD_LDS16(kq + lane * 8,        kl + lane * 8);                     \
        GLOAD_LDS16(kq + 512 + lane * 8,  kl + 512 + lane * 8);               \
        GLOAD_LDS16(kq + 1024 + lane * 8, kl + 1024 + lane * 8);              \
        GLOAD_LDS16(kq + 1536 + lane * 8, kl + 1536 + lane * 8);              \
        GLOAD_LDS16(vq + lane * 8,        vl + lane * 8);                     \
        GLOAD_LDS16(vq + 512 + lane * 8,  vl + 512 + lane * 8);               \
        GLOAD_LDS16(vq + 1024 + lane * 8, vl + 1024 + lane * 8);              \
        GLOAD_LDS16(vq + 1536 + lane * 8, vl + 1536 + lane * 8);              \
    } while (0)

    const int q = qt * 64 + wid * 16 + l15;

    F8 qf[2];
    {
        const unsigned short* qrow = qb + ((size_t)bh * SS + q) * 64;
        qf[0] = *(const F8*)(qrow + quad * 8);
        qf[1] = *(const F8*)(qrow + 32 + quad * 8);
    }

    STAGE(0, 0);
    __syncthreads();

    floatx4 accO[4];
#pragma unroll
    for (int dt = 0; dt < 4; ++dt) accO[dt] = (floatx4){0.f, 0.f, 0.f, 0.f};
    float lsum = 0.f;
    unsigned int* Pw = (unsigned int*)Ps + wid * 512;

    for (int qd = 0; qd < nq; ++qd) {
        if (qd + 1 < nq) STAGE(qd + 1, (qd + 1) & 1);
        const unsigned short* Ksb = Ks2[qd & 1];
        const unsigned short* Vsb = Vs2[qd & 1];
        const int sbase128 = qd * 128;

        // ---- S^T: 8 s-tiles of 16, computed only if tile's 64-chunk needed
        floatx4 accS[8];
#pragma unroll
        for (int st = 0; st < 8; ++st) {
            if (sbase128 + (st >> 2) * 64 <= qmaxw) {
                int srow = st * 16 + l15;
                const F8 k0 = *(const F8*)(Ksb + (((srow << 3) | ( quad      ^ (srow & 7))) << 3));
                const F8 k1 = *(const F8*)(Ksb + (((srow << 3) | ((4 + quad) ^ (srow & 7))) << 3));
                floatx4 a = (floatx4){0.f, 0.f, 0.f, 0.f};
                a = __builtin_amdgcn_mfma_f32_16x16x32_bf16(k0.s, qf[0].s, a, 0, 0, 0);
                a = __builtin_amdgcn_mfma_f32_16x16x32_bf16(k1.s, qf[1].s, a, 0, 0, 0);
                accS[st] = a;
            }
        }

        // ---- PV: 2 chunks of 64 s; skip chunks beyond causal bound
#pragma unroll
        for (int ch2 = 0; ch2 < 2; ++ch2) {
            if (sbase128 + ch2 * 64 > qmaxw) continue;   // wave-uniform skip
            unsigned int mw0 = maskg[(qd * 4 + ch2 * 2) * SS + q];
            unsigned int mw1 = maskg[(qd * 4 + ch2 * 2 + 1) * SS + q];
#pragma unroll
            for (int t = 0; t < 4; ++t) {
                unsigned int mw = (t & 2) ? mw1 : mw0;
                int sbase = (t & 1) * 16 + quad * 4;
                floatx4 a = accS[ch2 * 4 + t];
                float e0 = ((mw >> (sbase + 0)) & 1u) ? __expf(a[0] * SCALE_F) : 0.f;
                float e1 = ((mw >> (sbase + 1)) & 1u) ? __expf(a[1] * SCALE_F) : 0.f;
                float e2 = ((mw >> (sbase + 2)) & 1u) ? __expf(a[2] * SCALE_F) : 0.f;
                float e3 = ((mw >> (sbase + 3)) & 1u) ? __expf(a[3] * SCALE_F) : 0.f;
                lsum += (e0 + e1) + (e2 + e3);
                unsigned int w0 = (unsigned int)f2bf(e0) | ((unsigned int)f2bf(e1) << 16);
                unsigned int w1 = (unsigned int)f2bf(e2) | ((unsigned int)f2bf(e3) << 16);
                int off0 = t * 8 + quad * 2;
                int off1 = off0 + 1;
                Pw[l15 * 32 + ((((off0 >> 2) ^ (l15 & 7)) << 2) | (off0 & 3))] = w0;
                Pw[l15 * 32 + ((((off1 >> 2) ^ (l15 & 7)) << 2) | (off1 & 3))] = w1;
            }
            F8 pa[2];
#pragma unroll
            for (int ks = 0; ks < 2; ++ks) {
                int ci = ks * 4 + quad;
                pa[ks] = *(const F8*)((const unsigned short*)(Pw + l15 * 32) +
                                      ((ci ^ (l15 & 7)) << 3));
            }
#pragma unroll
            for (int dt = 0; dt < 4; ++dt) {
                int d = dt * 16 + l15;
#pragma unroll
                for (int ks = 0; ks < 2; ++ks) {
                    int scl = ch2 * 8 + ks * 4 + quad;
                    int chunk = d * 16 + (scl & 8) + ((scl ^ d) & 7);
                    const F8 bv = *(const F8*)(Vsb + ((size_t)chunk << 3));
                    accO[dt] = __builtin_amdgcn_mfma_f32_16x16x32_bf16(pa[ks].s, bv.s, accO[dt], 0, 0, 0);
                }
            }
        }
        __syncthreads();   // buffer reuse barrier (all waves iterate nq times)
    }

    lsum += __shfl_xor(lsum, 16);
    lsum += __shfl_xor(lsum, 32);
    float inv = 1.0f / lsum;

    unsigned short* Ow = Ps + wid * 1024;
#pragma unroll
    for (int r = 0; r < 4; ++r) {
        float invr = __shfl(inv, quad * 4 + r);
#pragma unroll
        for (int dt = 0; dt < 4; ++dt)
            Ow[(quad * 4 + r) * 64 + dt * 16 + l15] = f2bf(accO[dt][r] * invr);
    }
#pragma unroll
    for (int i = 0; i < 2; ++i) {
        int ch = i * 64 + lane;
        int qlocal = ch >> 3, j = ch & 7;
        int qq = qt * 64 + wid * 16 + qlocal;
        int mrow = b * SS + qq;
        int mt = mrow >> 7, rr = mrow & 127;
        int kt2 = h * 2 + (j >> 2), c = j & 3;
        size_t gid = (((size_t)(mt * 32 + kt2) * 4 + c) * 128 + rr);
        *(uint4*)(attn_sw + gid * 8) = *(const uint4*)(Ow + qlocal * 64 + j * 8);
    }
    #undef STAGE
}

// ---------------------------------------------------------------------------
extern "C" void kernel_launch(void* const* d_in, const int* in_sizes, int n_in,
                              void* d_out, int out_size, void* d_ws, size_t ws_size,
                              hipStream_t stream)
{
    const float* x     = (const float*)d_in[0];
    const float* w_qkv = (const float*)d_in[1];
    const float* b_qkv = (const float*)d_in[2];
    const float* w_out = (const float*)d_in[3];
    const float* b_out = (const float*)d_in[4];
    const int* routes  = (const int*)d_in[5];

    char* w = (char*)d_ws;
    unsigned short* xb_sw  = (unsigned short*)(w);                 // 4 MB
    unsigned short* wb1_sw = (unsigned short*)(w + (4u  << 20));   // 6 MB
    unsigned short* wb2_sw = (unsigned short*)(w + (10u << 20));   // 2 MB
    unsigned short* qbuf   = (unsigned short*)(w + (12u << 20));   // 4 MB
    unsigned short* kbuf   = (unsigned short*)(w + (16u << 20));   // 4 MB
    unsigned short* vbuf   = (unsigned short*)(w + (20u << 20));   // 4 MB
    unsigned short* K2g    = (unsigned short*)(w + (24u << 20));   // 4 MB
    unsigned short* Vtg    = (unsigned short*)(w + (28u << 20));   // 4 MB
    unsigned short* attnsw = (unsigned short*)(w + (32u << 20));   // 4 MB
    unsigned int*   maskg  = (unsigned int*)(w + (36u << 20));     // 32 KB

    prep_kernel<<<3074, 256, 0, stream>>>(x, w_qkv, w_out, routes,
                                          xb_sw, wb1_sw, wb2_sw, maskg);

    gemm_qkv<<<768, 256, 0, stream>>>(xb_sw, wb1_sw, b_qkv, qbuf, kbuf, vbuf);

    blend_kv_kernel<<<256, 256, 0, stream>>>(kbuf, vbuf, K2g, Vtg);

    attn_kernel<<<512, 256, 0, stream>>>(qbuf, K2g, Vtg, maskg, attnsw);

    gemm_out<<<512, 256, 0, stream>>>(attnsw, wb2_sw, b_out, (float*)d_out);
}